// Round 10
// baseline (581.732 us; speedup 1.0000x reference)
//
#include <hip/hip_runtime.h>
#include <hip/hip_bf16.h>
#include <math.h>

#define CDIV(a,b) (((a)+(b)-1)/(b))

typedef __bf16  bf16x8 __attribute__((ext_vector_type(8)));
typedef float   f32x4  __attribute__((ext_vector_type(4)));
typedef unsigned short u16x8 __attribute__((ext_vector_type(8)));
typedef unsigned short u16x4 __attribute__((ext_vector_type(4)));

__device__ __forceinline__ float bf2f(unsigned short u) {
    union { unsigned int i; float f; } x; x.i = ((unsigned int)u) << 16; return x.f;
}
__device__ __forceinline__ unsigned short f2bf(float f) {
    union { float f; unsigned int i; } x; x.f = f;
    unsigned int r = x.i + 0x7fff + ((x.i >> 16) & 1);   // RNE, finite inputs
    return (unsigned short)(r >> 16);
}

// Dword-wise bf16x8 -> f32x8: 4 shl + 4 and, guaranteed (R8 post-mortem).
__device__ __forceinline__ void bfx8_cvt(u16x8 v, float f[8]) {
    union { u16x8 v; unsigned d[4]; } u; u.v = v;
#pragma unroll
    for (int q = 0; q < 4; q++) {
        f[2*q]   = __uint_as_float(u.d[q] << 16);
        f[2*q+1] = __uint_as_float(u.d[q] & 0xffff0000u);
    }
}
__device__ __forceinline__ void bfx4_cvt(u16x4 v, float f[4]) {
    union { u16x4 v; unsigned d[2]; } u; u.v = v;
#pragma unroll
    for (int q = 0; q < 2; q++) {
        f[2*q]   = __uint_as_float(u.d[q] << 16);
        f[2*q+1] = __uint_as_float(u.d[q] & 0xffff0000u);
    }
}
// ELU with hardware exp: error < 1.2e-7 vs expm1f on v<=0, under bf16 rounding.
__device__ __forceinline__ float elu_fast(float v) {
    return (v > 0.f) ? v : (__expf(v) - 1.f);
}

// ---------------------------------------------------------------------------
// CSR build (by destination node). Edges = [E graph edges] + [n self-loops].
// ---------------------------------------------------------------------------
__global__ void hist_kernel(const int* __restrict__ ei, int* __restrict__ deg,
                            int E, int Et) {
    int e = blockIdx.x * blockDim.x + threadIdx.x;
    if (e >= Et) return;
    int d = (e < E) ? ei[E + e] : (e - E);
    atomicAdd(&deg[d], 1);
}

// Single-block exclusive scan, wave-shuffle based.
__global__ void scan_kernel(const int* __restrict__ deg, int* __restrict__ off, int n) {
    __shared__ int wsum[16];
    __shared__ int carry_s;
    int t = threadIdx.x, lane = t & 63, wv = t >> 6;
    if (t == 0) carry_s = 0;
    __syncthreads();
    for (int base = 0; base < n; base += 1024) {
        int v = (base + t < n) ? deg[base + t] : 0;
        int x = v;
#pragma unroll
        for (int o = 1; o < 64; o <<= 1) {
            int y = __shfl_up(x, o);
            if (lane >= o) x += y;
        }
        if (lane == 63) wsum[wv] = x;
        __syncthreads();
        if (wv == 0 && lane < 16) {
            int s = wsum[lane];
#pragma unroll
            for (int o = 1; o < 16; o <<= 1) {
                int y = __shfl_up(s, o);
                if (lane >= o) s += y;
            }
            wsum[lane] = s;
        }
        __syncthreads();
        int wprev = (wv == 0) ? 0 : wsum[wv - 1];
        int incl = carry_s + wprev + x;
        if (base + t < n) off[base + t] = incl - v;
        __syncthreads();
        if (t == 1023) carry_s = incl;
        __syncthreads();
    }
    if (t == 0) off[n] = carry_s;
}

__global__ void scatter_kernel(const int* __restrict__ ei, const int* __restrict__ off,
                               int* __restrict__ cur, int* __restrict__ csr,
                               int E, int Et) {
    int e = blockIdx.x * blockDim.x + threadIdx.x;
    if (e >= Et) return;
    int s, d;
    if (e < E) { s = ei[e]; d = ei[E + e]; } else { s = e - E; d = s; }
    int pos = off[d] + atomicAdd(&cur[d], 1);
    csr[pos] = s;
}

// ---------------------------------------------------------------------------
// Fused weight transpose+cvt: 3 jobs in one launch, 32x32 tiles.
// ---------------------------------------------------------------------------
__global__ void prep_t_kernel(const float* __restrict__ wa, __hip_bfloat16* __restrict__ wta,
                              const float* __restrict__ wb, __hip_bfloat16* __restrict__ wtb,
                              const float* __restrict__ wc, __hip_bfloat16* __restrict__ wtc,
                              int t0, int t1, int t2) {
    __shared__ float tile[32][33];
    int bid = blockIdx.x;
    const float* w; __hip_bfloat16* wt; int K, N, r;
    if (bid < t0)      { w = wa; wt = wta; K = 512;  N = 2048; r = bid; }
    else if (bid < t1) { w = wb; wt = wtb; K = 2048; N = 2048; r = bid - t0; }
    else               { w = wc; wt = wtc; K = 2048; N = 1024; r = bid - t1; }
    (void)t2;
    int kt = K >> 5;
    int kb = (r % kt) * 32, nb = (r / kt) * 32;
    int tx = threadIdx.x & 31, ty = threadIdx.x >> 5;
    for (int i = ty; i < 32; i += 8)
        tile[i][tx] = w[(size_t)(kb + i) * N + nb + tx];
    __syncthreads();
    for (int i = ty; i < 32; i += 8)
        wt[(size_t)(nb + i) * K + kb + tx] = __float2bfloat16(tile[tx][i]);
}

// Fused fp32->bf16 convert of proj_w then x (both sizes %4 == 0).
__global__ void cvt2_kernel(const float* __restrict__ a, __hip_bfloat16* __restrict__ ao,
                            int na4,
                            const float* __restrict__ b, __hip_bfloat16* __restrict__ bo,
                            int nb4) {
    int i = blockIdx.x * blockDim.x + threadIdx.x;
    const float* src; __hip_bfloat16* dst; int idx;
    if (i < na4) { src = a; dst = ao; idx = i * 4; }
    else if (i < na4 + nb4) { src = b; dst = bo; idx = (i - na4) * 4; }
    else return;
    float4 v = *(const float4*)(src + idx);
    dst[idx + 0] = __float2bfloat16(v.x);
    dst[idx + 1] = __float2bfloat16(v.y);
    dst[idx + 2] = __float2bfloat16(v.z);
    dst[idx + 3] = __float2bfloat16(v.w);
}

// b_eff[j] += partial over k-chunk of proj_b[k]*w1[k][j] (k-split, unrolled).
__global__ void beff_kernel(const float* __restrict__ pb, const float* __restrict__ w1,
                            float* __restrict__ beff, int N) {
    int j  = blockIdx.x * 256 + threadIdx.x;
    int k0 = blockIdx.y * 64;
    float s = 0.f;
#pragma unroll
    for (int k = 0; k < 64; k++)
        s = fmaf(pb[k0 + k], w1[(size_t)(k0 + k) * N + j], s);
    atomicAdd(&beff[j], s);
}

// ---------------------------------------------------------------------------
// va[j][256] = W_eff[:, head-block j] @ a_vec   (j<4: a_src head j; j>=4: a_dst)
// cvec[j] = b_eff[head-block] . a_vec ;  block 8 computes b1s = b_eff + b1.
// ---------------------------------------------------------------------------
__global__ void va_kernel(const __hip_bfloat16* __restrict__ w_efft,
                          const float* __restrict__ b_eff,
                          const float* __restrict__ as1, const float* __restrict__ ad1,
                          const float* __restrict__ b1,
                          float* __restrict__ va, float* __restrict__ cvec,
                          float* __restrict__ b1s) {
    int j = blockIdx.x, t = threadIdx.x;
    if (j == 8) {
        for (int i = t; i < 2048; i += 256) b1s[i] = b_eff[i] + b1[i];
        return;
    }
    int h = j & 3;
    const float* a = ((j < 4) ? as1 : ad1) + h * 512;
    __shared__ float aLDS[512];
    __shared__ float red[256];
    for (int c = t; c < 512; c += 256) aLDS[c] = a[c];
    __syncthreads();
    float acc = 0.f;
    const unsigned short* wb = (const unsigned short*)w_efft + (size_t)h * 512 * 256 + t;
    for (int c = 0; c < 512; c++)
        acc = fmaf(aLDS[c], bf2f(wb[(size_t)c * 256]), acc);
    va[j * 256 + t] = acc;
    float cp = b_eff[h * 512 + t] * aLDS[t] + b_eff[h * 512 + 256 + t] * aLDS[256 + t];
    red[t] = cp;
    __syncthreads();
    for (int s = 128; s > 0; s >>= 1) {
        if (t < s) red[t] += red[t + s];
        __syncthreads();
    }
    if (t == 0) cvec[j] = red[0];
}

// ---------------------------------------------------------------------------
// es1/ed1: es[node][h] = x_bf[node] . va[h] + cvec[h]  (one wave per node).
// ---------------------------------------------------------------------------
__global__ void es1_kernel(const __hip_bfloat16* __restrict__ x_bf,
                           const float* __restrict__ va, const float* __restrict__ cvec,
                           float* __restrict__ es, float* __restrict__ ed) {
    int node = blockIdx.x, l = threadIdx.x;
    u16x4 xv = *(const u16x4*)((const unsigned short*)x_bf + (size_t)node * 256 + l * 4);
    float xf[4];
    bfx4_cvt(xv, xf);
    float dot[8];
#pragma unroll
    for (int j = 0; j < 8; j++) {
        float4 v = *(const float4*)(va + j * 256 + l * 4);
        dot[j] = xf[0] * v.x + xf[1] * v.y + xf[2] * v.z + xf[3] * v.w;
    }
#pragma unroll
    for (int j = 0; j < 8; j++)
        for (int o = 32; o; o >>= 1) dot[j] += __shfl_down(dot[j], o);
    if (l == 0) {
#pragma unroll
        for (int h = 0; h < 4; h++) {
            es[node * 4 + h] = dot[h] + cvec[h];
            ed[node * 4 + h] = dot[4 + h] + cvec[4 + h];
        }
    }
}

// ---------------------------------------------------------------------------
// Layer-1 aggregation v3 in INPUT space (256 ch, 4 heads): one block per dst,
// FUSED softmax (denominator pass + inline alpha, removes alpha4 kernel).
// Pass A: 256 lanes stride edges -> per-head den partials -> shfl + LDS.
// Pass B: 4 waves process 4 edges concurrently, u16x4 vector gathers,
// alpha = exp(leaky(es+ed)) * inv_den recomputed inline (wave-uniform).
// ---------------------------------------------------------------------------
__global__ __launch_bounds__(256) void agg1x_kernel(
    const __hip_bfloat16* __restrict__ x_bf, const float* __restrict__ es,
    const float* __restrict__ ed, const int* __restrict__ csr,
    const int* __restrict__ off, __hip_bfloat16* __restrict__ z)
{
    __shared__ float red[4][1024];
    __shared__ float denS[4][4];   // [wave][head]
    int d = blockIdx.x, t = threadIdx.x;
    int w = t >> 6, l = t & 63;
    int c0 = l * 4;
    int beg = off[d], end = off[d + 1];
    float4 edv = *(const float4*)(ed + d * 4);
    float edd[4] = {edv.x, edv.y, edv.z, edv.w};

    // --- pass A: denominators ---
    float den[4] = {0.f, 0.f, 0.f, 0.f};
    for (int i = beg + t; i < end; i += 256) {
        int s = csr[i];
        float4 ev = *(const float4*)(es + s * 4);
        float e0 = ev.x + edd[0]; e0 = (e0 > 0.f) ? e0 : 0.2f * e0;
        float e1 = ev.y + edd[1]; e1 = (e1 > 0.f) ? e1 : 0.2f * e1;
        float e2 = ev.z + edd[2]; e2 = (e2 > 0.f) ? e2 : 0.2f * e2;
        float e3 = ev.w + edd[3]; e3 = (e3 > 0.f) ? e3 : 0.2f * e3;
        den[0] += __expf(e0); den[1] += __expf(e1);
        den[2] += __expf(e2); den[3] += __expf(e3);
    }
#pragma unroll
    for (int h = 0; h < 4; h++)
        for (int o = 32; o; o >>= 1) den[h] += __shfl_down(den[h], o);
    if (l == 0) {
#pragma unroll
        for (int h = 0; h < 4; h++) denS[w][h] = den[h];
    }
    __syncthreads();
    float inv[4];
#pragma unroll
    for (int h = 0; h < 4; h++)
        inv[h] = 1.f / (denS[0][h] + denS[1][h] + denS[2][h] + denS[3][h]);

    // --- pass B: gather + weighted accumulate ---
    float acc[4][4] = {};   // [k (ch)][h (head)]
    const unsigned short* xb = (const unsigned short*)x_bf;
    for (int i = beg + w; i < end; i += 4) {
        int s = csr[i];
        float4 ev = *(const float4*)(es + s * 4);
        float a[4];
        {
            float e0 = ev.x + edd[0]; e0 = (e0 > 0.f) ? e0 : 0.2f * e0;
            float e1 = ev.y + edd[1]; e1 = (e1 > 0.f) ? e1 : 0.2f * e1;
            float e2 = ev.z + edd[2]; e2 = (e2 > 0.f) ? e2 : 0.2f * e2;
            float e3 = ev.w + edd[3]; e3 = (e3 > 0.f) ? e3 : 0.2f * e3;
            a[0] = __expf(e0) * inv[0]; a[1] = __expf(e1) * inv[1];
            a[2] = __expf(e2) * inv[2]; a[3] = __expf(e3) * inv[3];
        }
        u16x4 xv = *(const u16x4*)(xb + (size_t)s * 256 + c0);
        float xf[4];
        bfx4_cvt(xv, xf);
#pragma unroll
        for (int k = 0; k < 4; k++) {
            acc[k][0] = fmaf(a[0], xf[k], acc[k][0]);
            acc[k][1] = fmaf(a[1], xf[k], acc[k][1]);
            acc[k][2] = fmaf(a[2], xf[k], acc[k][2]);
            acc[k][3] = fmaf(a[3], xf[k], acc[k][3]);
        }
    }
#pragma unroll
    for (int h = 0; h < 4; h++)
#pragma unroll
        for (int k = 0; k < 4; k++)
            red[w][h * 256 + c0 + k] = acc[k][h];
    __syncthreads();
    unsigned short* zb = (unsigned short*)z + (size_t)d * 1024;
#pragma unroll
    for (int q = 0; q < 4; q++) {
        int m = t + q * 256;
        float v = red[0][m] + red[1][m] + red[2][m] + red[3][m];
        zb[m] = f2bf(v);
    }
}

// ---------------------------------------------------------------------------
// bf16 MFMA GEMM: Cb[M,N] = bf16(act( A[M,K(lda)] @ BT[N,K]^T + bias ))
// 128x128 tile, BK=32, 256 threads (4 waves), 16x16x32 MFMA. 3 blk/CU.
// Used for the fold-GEMM and the L1 GEMM (K=256: shallow-K wants small tiles
// + multi-block-per-CU occupancy -- R7 post-mortem).
// ---------------------------------------------------------------------------
__device__ __forceinline__ void gload16(void* lds, const void* g) {
    __builtin_amdgcn_global_load_lds(
        (const __attribute__((address_space(1))) void*)g,
        (__attribute__((address_space(3))) void*)lds, 16, 0, 0);
}

__global__ __launch_bounds__(256) void gemm_bf16_kernel(
    const __hip_bfloat16* __restrict__ A,
    const __hip_bfloat16* __restrict__ BT,
    const float* __restrict__ bias,
    __hip_bfloat16* __restrict__ Cb,
    int M, int N, int K, int lda, int hko, int do_elu,
    int MB, int NB, int XT, int NBH)
{
    __shared__ __align__(16) __hip_bfloat16 As[128 * 32];
    __shared__ __align__(16) __hip_bfloat16 Bs[128 * 32];

    const int bid  = blockIdx.x;
    const int xcd  = bid & 7;
    const int slot = bid >> 3;
    const int per_yh = XT * NBH;
    const int yh    = slot / per_yh;
    const int rem   = slot - yh * per_yh;
    const int x_sub = rem / NBH;
    const int ys    = rem - x_sub * NBH;
    const int yb    = yh * NBH + ys;
    const int xb    = xcd * XT + x_sub;
    if (xb >= MB || yb >= NB) return;

    const int tid = threadIdx.x;
    const int m0 = xb * 128, n0 = yb * 128;
    const int w = tid >> 6, l = tid & 63;
    const int wm = (w & 1) * 64, wn = (w >> 1) * 64;
    const int lm = l & 15, lq = l >> 4;

    f32x4 acc[4][4] = {};

    const int arow = tid >> 2;
    const int acol = (tid & 3) * 8;
    const __hip_bfloat16* Ag = A + (size_t)(m0 + arow) * lda + acol + (n0 >> 9) * hko;
    const __hip_bfloat16* Bg = BT + (size_t)(n0 + arow) * K + acol;
    char* AsW = (char*)As + (w << 10);
    char* BsW = (char*)Bs + (w << 10);

    for (int k0 = 0; k0 < K; k0 += 32) {
        gload16(AsW,        Ag + k0);
        gload16(AsW + 4096, Ag + (size_t)64 * lda + k0);
        gload16(BsW,        Bg + k0);
        gload16(BsW + 4096, Bg + (size_t)64 * K + k0);
        __syncthreads();
        bf16x8 af[4], bfr[4];
#pragma unroll
        for (int i = 0; i < 4; i++)
            af[i] = *(const bf16x8*)(As + (wm + i * 16 + lm) * 32 + lq * 8);
#pragma unroll
        for (int j = 0; j < 4; j++)
            bfr[j] = *(const bf16x8*)(Bs + (wn + j * 16 + lm) * 32 + lq * 8);
#pragma unroll
        for (int i = 0; i < 4; i++)
#pragma unroll
            for (int j = 0; j < 4; j++)
                acc[i][j] = __builtin_amdgcn_mfma_f32_16x16x32_bf16(
                    af[i], bfr[j], acc[i][j], 0, 0, 0);
        __syncthreads();
    }

#pragma unroll
    for (int i = 0; i < 4; i++) {
        int rb = m0 + wm + i * 16 + lq * 4;
#pragma unroll
        for (int r = 0; r < 4; r++) {
            int row = rb + r;
            if (row >= M) continue;
#pragma unroll
            for (int j = 0; j < 4; j++) {
                int col = n0 + wn + j * 16 + lm;
                float v = acc[i][j][r];
                if (bias) v += bias[col];
                if (do_elu) v = elu_fast(v);
                Cb[(size_t)row * N + col] = __float2bfloat16(v);
            }
        }
    }
}

// ---------------------------------------------------------------------------
// 256x256 8-phase bf16 GEMM (T2+T3+T4+T5 template, plain HIP). K>=1024 only.
//   slot < nfull  -> (mt = slot % MT, ntl = slot / MT)
//   slot >= nfull -> (ntl = nfull/MT, mt = nfull%MT + slot - nfull)
// ---------------------------------------------------------------------------
__global__ __launch_bounds__(512, 2) void gemm256_kernel(
    const __hip_bfloat16* __restrict__ A,
    const __hip_bfloat16* __restrict__ BT,
    __hip_bfloat16* __restrict__ Cb,
    int M, int N, int K, int MT, int nfull)
{
    __shared__ __align__(16) char smem[131072];
    const int NT = K >> 6;

    const int cpx  = gridDim.x >> 3;
    const int bid  = blockIdx.x;
    const int slot = (bid & 7) * cpx + (bid >> 3);
    int mt, ntl;
    if (slot < nfull) { mt = slot % MT; ntl = slot / MT; }
    else              { ntl = nfull / MT; mt = (nfull % MT) + (slot - nfull); }
    const int m0 = mt << 8, n0 = ntl << 8;

    const int tid = threadIdx.x;
    const int w  = tid >> 6, l = tid & 63;
    const int wr = w >> 2, wc = w & 3;        // 2 M-waves x 4 N-waves
    const int lm = l & 15, lq = l >> 4;

    // --- staging constants (linear LDS dest, inverse-swizzled global src) ---
    const int srow = tid >> 3;                           // 0..63
    const int scol = ((l & 7) << 3) ^ ((l >> 3) << 3);   // bf16 col, 16B-aligned
    const __hip_bfloat16* As0 = A  + (size_t)(m0 + srow) * K + scol;
    const __hip_bfloat16* Bs0 = BT + (size_t)(n0 + srow) * K + scol;
    const size_t rs64  = (size_t)64  * K;
    const size_t rs128 = (size_t)128 * K;
    char* const stA = smem +          ((size_t)w << 10);
    char* const stB = smem + 65536 +  ((size_t)w << 10);

    auto STAGE_A = [&](int par, int hf, int tt) {
        char* d = stA + (((par << 1) | hf) << 14);
        const __hip_bfloat16* s = As0 + (size_t)hf * rs128 + (tt << 6);
        gload16(d,        s);
        gload16(d + 8192, s + rs64);
    };
    auto STAGE_B = [&](int par, int hf, int tt) {
        char* d = stB + (((par << 1) | hf) << 14);
        const __hip_bfloat16* s = Bs0 + (size_t)hf * rs128 + (tt << 6);
        gload16(d,        s);
        gload16(d + 8192, s + rs64);
    };

    // --- ds_read constants (swizzled) ---
    const int roff = lm << 7;                 // row-within-16 block * 128B
    const int xm   = (lm & 7) << 4;
    const int off0 = (lq << 4) ^ xm;          // kk = 0
    const int off1 = off0 ^ 64;               // kk = 1
    const int bsel = 65536 + ((wc & 1) << 13);

    f32x4  acc[8][4] = {};
    bf16x8 af[8][2];
    bf16x8 bfr[2][2];

    // --- prologue: half-tiles h=0..5 ---
    STAGE_A(0, 0, 0); STAGE_A(0, 1, 0);
    STAGE_B(0, 0, 0); STAGE_B(0, 1, 0);
    STAGE_A(1, 0, 1); STAGE_A(1, 1, 1);
    asm volatile("s_waitcnt vmcnt(4)" ::: "memory");
    __builtin_amdgcn_s_barrier();

    for (int t = 0; t < NT; ++t) {
        const int par = t & 1;
        const char* aS = smem + (((par << 1) | wr)        << 14) + roff;
        const char* bS = smem + (((par << 1) | (wc >> 1)) << 14) + bsel + roff;

        // ===== phase 0 : Q1 (Mlo x Nlo) =====
#pragma unroll
        for (int i = 0; i < 4; ++i) {
            af[i][0] = *(const bf16x8*)(aS + i * 2048 + off0);
            af[i][1] = *(const bf16x8*)(aS + i * 2048 + off1);
        }
#pragma unroll
        for (int j = 0; j < 2; ++j) {
            bfr[j][0] = *(const bf16x8*)(bS + j * 2048 + off0);
            bfr[j][1] = *(const bf16x8*)(bS + j * 2048 + off1);
        }
        if (t + 1 < NT) STAGE_B(par ^ 1, 0, t + 1);
        __builtin_amdgcn_s_barrier();
        asm volatile("s_waitcnt lgkmcnt(0)" ::: "memory");
        __builtin_amdgcn_sched_barrier(0);
        __builtin_amdgcn_s_setprio(1);
#pragma unroll
        for (int i = 0; i < 4; ++i)
#pragma unroll
            for (int j = 0; j < 2; ++j) {
                acc[i][j] = __builtin_amdgcn_mfma_f32_16x16x32_bf16(af[i][0], bfr[j][0], acc[i][j], 0, 0, 0);
                acc[i][j] = __builtin_amdgcn_mfma_f32_16x16x32_bf16(af[i][1], bfr[j][1], acc[i][j], 0, 0, 0);
            }
        __builtin_amdgcn_s_setprio(0);
        __builtin_amdgcn_s_barrier();

        // ===== phase 1 : Q2 (Mhi x Nlo) =====
#pragma unroll
        for (int i = 4; i < 8; ++i) {
            af[i][0] = *(const bf16x8*)(aS + i * 2048 + off0);
            af[i][1] = *(const bf16x8*)(aS + i * 2048 + off1);
        }
        if (t + 1 < NT) STAGE_B(par ^ 1, 1, t + 1);
        __builtin_amdgcn_s_barrier();
        asm volatile("s_waitcnt lgkmcnt(0)" ::: "memory");
        __builtin_amdgcn_sched_barrier(0);
        __builtin_amdgcn_s_setprio(1);
#pragma unroll
        for (int i = 4; i < 8; ++i)
#pragma unroll
            for (int j = 0; j < 2; ++j) {
                acc[i][j] = __builtin_amdgcn_mfma_f32_16x16x32_bf16(af[i][0], bfr[j][0], acc[i][j], 0, 0, 0);
                acc[i][j] = __builtin_amdgcn_mfma_f32_16x16x32_bf16(af[i][1], bfr[j][1], acc[i][j], 0, 0, 0);
            }
        __builtin_amdgcn_s_setprio(0);
        __builtin_amdgcn_s_barrier();

        // ===== phase 2 : Q3 (Mlo x Nhi) =====
#pragma unroll
        for (int j = 0; j < 2; ++j) {
            bfr[j][0] = *(const bf16x8*)(bS + (j + 2) * 2048 + off0);
            bfr[j][1] = *(const bf16x8*)(bS + (j + 2) * 2048 + off1);
        }
        if (t + 2 < NT) STAGE_A(par, 0, t + 2);
        __builtin_amdgcn_s_barrier();
        asm volatile("s_waitcnt lgkmcnt(0)" ::: "memory");
        __builtin_amdgcn_sched_barrier(0);
        __builtin_amdgcn_s_setprio(1);
#pragma unroll
        for (int i = 0; i < 4; ++i)
#pragma unroll
            for (int j = 0; j < 2; ++j) {
                acc[i][j + 2] = __builtin_amdgcn_mfma_f32_16x16x32_bf16(af[i][0], bfr[j][0], acc[i][j + 2], 0, 0, 0);
                acc[i][j + 2] = __builtin_amdgcn_mfma_f32_16x16x32_bf16(af[i][1], bfr[j][1], acc[i][j + 2], 0, 0, 0);
            }
        __builtin_amdgcn_s_setprio(0);
        __builtin_amdgcn_s_barrier();

        // ===== phase 3 : Q4 (Mhi x Nhi) =====
        if (t + 2 < NT) STAGE_A(par, 1, t + 2);
        __builtin_amdgcn_s_barrier();
        __builtin_amdgcn_sched_barrier(0);
        __builtin_amdgcn_s_setprio(1);
#pragma unroll
        for (int i = 4; i < 8; ++i)
#pragma unroll
            for (int j = 0; j < 2; ++j) {
                acc[i][j + 2] = __builtin_amdgcn_mfma_f32_16x16x32_bf16(af[i][0], bfr[j][0], acc[i][j + 2], 0, 0, 0);
                acc[i][j + 2] = __builtin_amdgcn_mfma_f32_16x16x32_bf16(af[i][1], bfr[j][1], acc[i][j + 2], 0, 0, 0);
            }
        __builtin_amdgcn_s_setprio(0);
        if (t + 2 < NT)      { asm volatile("s_waitcnt vmcnt(4)" ::: "memory"); }
        else if (t + 1 < NT) { asm volatile("s_waitcnt vmcnt(0)" ::: "memory"); }
        __builtin_amdgcn_s_barrier();
    }

    // --- epilogue: C write (row-guarded; pad rows discarded) ---
#pragma unroll
    for (int i = 0; i < 8; ++i) {
        int rb = m0 + wr * 128 + i * 16 + lq * 4;
#pragma unroll
        for (int r = 0; r < 4; ++r) {
            int row = rb + r;
            if (row >= M) continue;
#pragma unroll
            for (int j = 0; j < 4; ++j) {
                int col = n0 + wc * 64 + j * 16 + lm;
                Cb[(size_t)row * N + col] = __float2bfloat16(acc[i][j][r]);
            }
        }
    }
}

// ---------------------------------------------------------------------------
// 128x128 bf16 GEMM, BK=64, 256 thr (4 waves 2x2), 64 KiB dbuf LDS (2 blk/CU).
// mode 0: r = slot % RT, c = slot / RT          (layer 3: grid 640, RT=80)
// mode 1: layer-2 remainder of the 40x8 256-tile space after 256 big tiles.
// ---------------------------------------------------------------------------
__global__ __launch_bounds__(256, 2) void gemm128_kernel(
    const __hip_bfloat16* __restrict__ A,
    const __hip_bfloat16* __restrict__ BT,
    __hip_bfloat16* __restrict__ Cb,
    int M, int N, int K, int mode, int RT)
{
    __shared__ __align__(16) char smem[65536];
    const int NT = K >> 6;

    const int cpx  = gridDim.x >> 3;
    const int bid  = blockIdx.x;
    const int slot = (bid & 7) * cpx + (bid >> 3);
    int r, c;
    if (mode == 0) { r = slot % RT; c = slot / RT; }
    else {
        if (slot < 96) { c = 12 + slot / 48; r = 32 + slot % 48; }
        else           { int u = slot - 96; c = 14 + u / 80; r = u % 80; }
    }
    const int m0 = r << 7, n0 = c << 7;

    const int tid = threadIdx.x;
    const int w = tid >> 6, l = tid & 63;
    const int wm = (w & 1) << 6, wn = (w >> 1) << 6;
    const int lm = l & 15, lq = l >> 4;

    // staging: 16 KiB/operand/tile = 4 sweeps of 4 KiB (32 rows each)
    const int srow = tid >> 3;                                  // 0..31
    const int scol = (((tid & 7) ^ ((tid >> 3) & 7)) << 3);     // bf16 col
    const __hip_bfloat16* Ag = A  + (size_t)(m0 + srow) * K + scol;
    const __hip_bfloat16* Bg = BT + (size_t)(n0 + srow) * K + scol;
    const size_t rs32 = (size_t)32 * K;
    char* const dA = smem +         ((size_t)w << 10);
    char* const dB = smem + 16384 + ((size_t)w << 10);

    auto STAGE = [&](int par, int tt) {
        char* pa = dA + (par << 15);
        char* pb = dB + (par << 15);
        const __hip_bfloat16* sa = Ag + (tt << 6);
        const __hip_bfloat16* sb = Bg + (tt << 6);
#pragma unroll
        for (int s = 0; s < 4; ++s) {
            gload16(pa + (s << 12), sa + (size_t)s * rs32);
            gload16(pb + (s << 12), sb + (size_t)s * rs32);
        }
    };

    const int roff = lm << 7;
    const int off0 = (lq << 4) ^ ((lm & 7) << 4);
    const int off1 = off0 ^ 64;

    f32x4 acc[4][4] = {};

    STAGE(0, 0);
    asm volatile("s_waitcnt vmcnt(0)" ::: "memory");
    __builtin_amdgcn_s_barrier();

    for (int t = 0; t < NT; ++t) {
        const int par = t & 1;
        if (t + 1 < NT) STAGE(par ^ 1, t + 1);
        const char* aS = smem + (par << 15) +         wm * 128 + roff;
        const char* bS = smem + (par << 15) + 16384 + wn * 128 + roff;
        bf16x8 af[4][2], bfr[4][2];
#pragma unroll
        for (int i = 0; i < 4; ++i) {
            af[i][0]  = *(const bf16x8*)(aS + i * 2048 + off0);
            af[i][1]  = *(const bf16x8*)(aS + i * 2048 + off1);
            bfr[i][0] = *(const bf16x8*)(bS + i * 2048 + off0);
            bfr[i][1] = *(const bf16x8*)(bS + i * 2048 + off1);
        }
        asm volatile("s_waitcnt lgkmcnt(0)" ::: "memory");
        __builtin_amdgcn_sched_barrier(0);
        __builtin_amdgcn_s_setprio(1);
#pragma unroll
        for (int i = 0; i < 4; ++i)
#pragma unroll
            for (int j = 0; j < 4; ++j) {
                acc[i][j] = __builtin_amdgcn_mfma_f32_16x16x32_bf16(af[i][0], bfr[j][0], acc[i][j], 0, 0, 0);
                acc[i][j] = __builtin_amdgcn_mfma_f32_16x16x32_bf16(af[i][1], bfr[j][1], acc[i][j], 0, 0, 0);
            }
        __builtin_amdgcn_s_setprio(0);
        if (t + 1 < NT) asm volatile("s_waitcnt vmcnt(0)" ::: "memory");
        __builtin_amdgcn_s_barrier();
    }

#pragma unroll
    for (int i = 0; i < 4; ++i) {
        int rb = m0 + wm + i * 16 + lq * 4;
#pragma unroll
        for (int r2 = 0; r2 < 4; ++r2) {
            int row = rb + r2;
            if (row >= M) continue;
#pragma unroll
            for (int j = 0; j < 4; ++j) {
                int col = n0 + wn + j * 16 + lm;
                Cb[(size_t)row * N + col] = __float2bfloat16(acc[i][j][r2]);
            }
        }
    }
}

// ---------------------------------------------------------------------------
// es/ed: per-node per-head dot with a_src/a_dst (h in bf16). One wave/head.
// ---------------------------------------------------------------------------
__global__ void esed_kernel(const __hip_bfloat16* __restrict__ h,
                            const float* __restrict__ a_src,
                            const float* __restrict__ a_dst,
                            float* __restrict__ es, float* __restrict__ ed, int H) {
    int nidx = blockIdx.x;
    int t = threadIdx.x;
    int head = t >> 6, lane = t & 63;
    const unsigned short* hp =
        (const unsigned short*)h + (size_t)nidx * H * 512 + head * 512 + lane * 8;
    const float* sp = a_src + head * 512 + lane * 8;
    const float* dp = a_dst + head * 512 + lane * 8;
    u16x8 hv = *(const u16x8*)hp;
    float4 s0 = *(const float4*)sp, s1 = *(const float4*)(sp + 4);
    float4 d0 = *(const float4*)dp, d1 = *(const float4*)(dp + 4);
    float hf[8];
    bfx8_cvt(hv, hf);
    float s = hf[0]*s0.x + hf[1]*s0.y + hf[2]*s0.z + hf[3]*s0.w
            + hf[4]*s1.x + hf[5]*s1.y + hf[6]*s1.z + hf[7]*s1.w;
    float d = hf[0]*d0.x + hf[1]*d0.y + hf[2]*d0.z + hf[3]*d0.w
            + hf[4]*d1.x + hf[5]*d1.y + hf[6]*d1.z + hf[7]*d1.w;
    for (int o = 32; o; o >>= 1) { s += __shfl_down(s, o); d += __shfl_down(d, o); }
    if (lane == 0) { es[nidx * H + head] = s; ed[nidx * H + head] = d; }
}

// ---------------------------------------------------------------------------
// alpharec: per (edge, head) record {row_byte_offset = src << SHIFT, alpha}.
// One wave per dst; alpha = exp(leaky(es+ed)) / den.
// ---------------------------------------------------------------------------
template<int H, int SHIFT>
__global__ __launch_bounds__(256) void alpharec_kernel(
    const float* __restrict__ es, const float* __restrict__ ed,
    const int* __restrict__ csr, const int* __restrict__ off,
    uint2* __restrict__ rec, int n)
{
    int d = blockIdx.x * 4 + (threadIdx.x >> 6);
    if (d >= n) return;
    int lane = threadIdx.x & 63;
    int beg = off[d], end = off[d + 1];
    float edd[H], den[H];
#pragma unroll
    for (int h = 0; h < H; h++) { edd[h] = ed[d * H + h]; den[h] = 0.f; }
    for (int i = beg + lane; i < end; i += 64) {
        int s = csr[i];
#pragma unroll
        for (int h = 0; h < H; h++) {
            float e = es[s * H + h] + edd[h];
            e = (e > 0.f) ? e : 0.2f * e;
            den[h] += __expf(e);
        }
    }
#pragma unroll
    for (int h = 0; h < H; h++) {
        for (int o = 32; o; o >>= 1) den[h] += __shfl_down(den[h], o);
        den[h] = __shfl(den[h], 0);
        den[h] = 1.f / den[h];
    }
    for (int i = beg + lane; i < end; i += 64) {
        int s = csr[i];
        unsigned obytes = ((unsigned)s) << SHIFT;
#pragma unroll
        for (int h = 0; h < H; h++) {
            float e = es[s * H + h] + edd[h];
            e = (e > 0.f) ? e : 0.2f * e;
            float a = __expf(e) * den[h];
            rec[(size_t)i * H + h] = make_uint2(obytes, __float_as_uint(a));
        }
    }
}

// ---------------------------------------------------------------------------
// Layer-2 aggregation v3: XCD-pinned 256-ch slices (L2-resident working set),
// half-wave u16x8 gathers, precomputed {offset,alpha} records, dword cvt.
// ---------------------------------------------------------------------------
__global__ __launch_bounds__(256) void agg2s_kernel(
    const __hip_bfloat16* __restrict__ h, const uint2* __restrict__ rec,
    const int* __restrict__ off, const float* __restrict__ bias,
    __hip_bfloat16* __restrict__ outB, int n)
{
    const int bid   = blockIdx.x;
    const int slice = bid & 7;
    const int head  = slice >> 1;
    const int wvs   = (bid >> 3) * 4 + (threadIdx.x >> 6);   // 0..1023
    const int lane  = threadIdx.x & 63;
    const int half  = lane >> 5;
    const int c0    = slice * 256 + (lane & 31) * 8;
    const unsigned c0b = (unsigned)c0 * 2;                   // byte offset in row
    const char* hb = (const char*)h;
    float bv[8];
#pragma unroll
    for (int k = 0; k < 8; k++) bv[k] = bias[c0 + k];

    for (int d = wvs; d < n; d += 1024) {
        int beg = off[d], end = off[d + 1];
        float acc[8] = {0.f, 0.f, 0.f, 0.f, 0.f, 0.f, 0.f, 0.f};
        int i = beg + half;
        for (; i + 2 < end; i += 4) {        // 2 edges per half per iter
            uint2 r0 = rec[i * 4 + head];
            uint2 r1 = rec[(i + 2) * 4 + head];
            u16x8 v0 = *(const u16x8*)(hb + (size_t)(r0.x + c0b));
            u16x8 v1 = *(const u16x8*)(hb + (size_t)(r1.x + c0b));
            float a0 = __uint_as_float(r0.y);
            float a1 = __uint_as_float(r1.y);
            float f0[8], f1[8];
            bfx8_cvt(v0, f0);
            bfx8_cvt(v1, f1);
#pragma unroll
            for (int k = 0; k < 8; k++) acc[k] = fmaf(a0, f0[k], acc[k]);
#pragma unroll
            for (int k = 0; k < 8; k++) acc[k] = fmaf(a1, f1[k], acc[k]);
        }
        for (; i < end; i += 2) {
            uint2 r0 = rec[i * 4 + head];
            u16x8 v0 = *(const u16x8*)(hb + (size_t)(r0.x + c0b));
            float a0 = __uint_as_float(r0.y);
            float f0[8];
            bfx8_cvt(v0, f0);
#pragma unroll
            for (int k = 0; k < 8; k++) acc[k] = fmaf(a0, f0[k], acc[k]);
        }
#pragma unroll
        for (int k = 0; k < 8; k++) acc[k] += __shfl_xor(acc[k], 32);
        if (half == 0) {
            u16x8 ov;
#pragma unroll
            for (int k = 0; k < 8; k++) {
                float v = elu_fast(acc[k] + bv[k]);
                ov[k] = f2bf(v);
            }
            *(u16x8*)((unsigned short*)outB + (size_t)d * 2048 + c0) = ov;
        }
    }
}

// ---------------------------------------------------------------------------
// Layer-3 aggregation v5: DIRECT OUTPUT. 2 slices of 256 out-ch (c<512);
// each wave gathers BOTH heads of its slice (head0 at c0, head1 at 1024+c0
// bytes; both records for an edge arrive in one aligned uint4) and writes
// 0.5*(sum_h0 + sum_h1) + b3 straight to d_out. Removes the part buffer
// (40MB write) and the comb3 pass (60MB traffic + a launch). No atomics
// (R5 post-mortem). Accumulation interleaves heads (sub-ulp vs part-based).
// ---------------------------------------------------------------------------
__global__ __launch_bounds__(256) void agg3s_kernel(
    const __hip_bfloat16* __restrict__ h, const uint2* __restrict__ rec,
    const int* __restrict__ off, const float* __restrict__ b3,
    float* __restrict__ out, int n)
{
    const int bid   = blockIdx.x;
    const int slice = bid & 1;                        // XCD-parity pinning
    const int sb    = bid >> 1;                       // 0..1023
    const int wvs   = sb * 4 + (threadIdx.x >> 6);    // 0..4095
    const int lane  = threadIdx.x & 63;
    const int half  = lane >> 5;
    const int c0    = slice * 256 + (lane & 31) * 8;  // out channel < 512
    const unsigned c0b = (unsigned)c0 * 2;            // head0 byte offset
    const char* hb = (const char*)h;
    float bv[8];
#pragma unroll
    for (int k = 0; k < 8; k++) bv[k] = b3[c0 + k];

    for (int d = wvs; d < n; d += 4096) {
        int beg = off[d], end = off[d + 1];
        float acc[8] = {0.f, 0.f, 0.f, 0.f, 0.f, 0.f, 0.f, 0.f};
        int i = beg + half;
        for (; i + 2 < end; i += 4) {                 // 2 edges/half/iter
            uint4 r0 = *(const uint4*)(rec + (size_t)i * 2);
            uint4 r1 = *(const uint4*)(rec + (size_t)(i + 2) * 2);
            u16x8 v00 = *(const u16x8*)(hb + (size_t)(r0.x + c0b));
            u16x8 v01 = *(const u16x8*)(hb + (size_t)(r0.x + 1024 + c0b));
            u16x8 v10 = *(const u16x8*)(hb + (size_t)(r1.x + c0b));
            u16x8 v11 = *(const u16x8*)(hb + (size_t)(r1.x + 1024 + c0b));
            float a00 = __uint_as_float(r0.y), a01 = __uint_as_float(r0.w);
            float a10 = __uint_as_float(r1.y), a11 = __uint_as_float(r1.w);
            float f[8];
            bfx8_cvt(v00, f);
#pragma unroll
            for (int k = 0; k < 8; k++) acc[k] = fmaf(a00, f[k], acc[k]);
            bfx8_cvt(v01, f);
#pragma unroll
            for (int k = 0; k < 8; k++) acc[k] = fmaf(a01, f[k], acc[k]);
            bfx8_cvt(v10, f);
#pragma unroll
            for (int k = 0; k < 8; k++) acc[k] = fmaf(a10, f[k], acc[k]);
            bfx8_cvt(v11, f);
#pragma unroll
            for (int k = 0; k < 8; k++) acc[k] = fmaf(a11, f[k], acc[k]);
        }
        for (; i < end; i += 2) {
            uint4 r0 = *(const uint4*)(rec + (size_t)i * 2);
            u16x8 v00 = *(const u16x8*)(hb + (size_t)(r0.x + c0b));
            u16x8 v01 = *(const u16x8*)(hb + (size_t)(r0.x + 1024 + c0b));
            float a00 = __uint_as_float(r0.y), a01 = __uint_as_float(r0.w);
            float f[8];
            bfx8_cvt(v00, f);
#pragma unroll
            for (int k = 0; k < 8; k++) acc[k] = fmaf(a00, f[k], acc[k]);
            bfx8_cvt(v01, f);
#pragma unroll
            for (int k = 0; k < 8; k++) acc[k] = fmaf(a01, f[k], acc[k]);
        }
#pragma unroll
        for (int k = 0; k < 8; k++) acc[k] += __shfl_xor(acc[k], 32);
        if (half == 0) {
            float* op = out + (size_t)d * 512 + c0;
            float4 o0, o1;
            o0.x = 0.5f * acc[0] + bv[0]; o0.y = 0.5f * acc[1] + bv[1];
            o0.z = 0.5f * acc[2] + bv[2]; o0.w = 0.5f * acc[3] + bv[3];
            o1.x = 0.5f * acc[4] + bv[4]; o1.y = 0.5f * acc[5] + bv[5];
            o1.z = 0.5f * acc[6] + bv[6]; o1.w = 0.5f * acc[7] + bv[7];
            *(float4*)op       = o0;
            *(float4*)(op + 4) = o1;
        }
    }
}

// ---------------------------------------------------------------------------
extern "C" void kernel_launch(void* const* d_in, const int* in_sizes, int n_in,
                              void* d_out, int out_size, void* d_ws, size_t ws_size,
                              hipStream_t stream) {
    const float* x      = (const float*)d_in[0];
    const int*   ei     = (const int*)  d_in[1];
    const float* proj_w = (const float*)d_in[2];
    const float* proj_b = (const float*)d_in[3];
    const float* w1  = (const float*)d_in[4];
    const float* as1 = (const float*)d_in[5];
    const float* ad1 = (const float*)d_in[6];
    const float* b1  = (const float*)d_in[7];
    const float* w2  = (const float*)d_in[8];
    const float* as2 = (const float*)d_in[9];
    const float* ad2 = (const float*)d_in[10];
    const float* b2  = (const float*)d_in[11];
    const float* w3  = (const float*)d_in[12];
    const float* as3 = (const float*)d_in[13];
    const float* ad3 = (const float*)d_in[14];
    const float* b3  = (const float*)d_in[15];

    const int n    = in_sizes[0] / 256;   // 10000
    const int E    = in_sizes[1] / 2;     // 160000
    const int Et   = E + n;               // 170000
    const int MB   = CDIV(n, 128);        // 79  (128-tile grid, layer 1)
    const int MB2  = CDIV(n, 256);        // 40  (256-tile grid)
    const int Mpad = MB2 * 256;           // 10240
    const int XT   = CDIV(MB, 8);         // 10

    char* p = (char*)d_ws;
    auto carve = [&](size_t bytes) {
        void* r = (void*)p;
        p += (bytes + 255) & ~(size_t)255;
        return r;
    };
    __hip_bfloat16* h_bf    = (__hip_bfloat16*)carve((size_t)Mpad * 2048 * sizeof(__hip_bfloat16));
    __hip_bfloat16* act_bf  = (__hip_bfloat16*)carve((size_t)Mpad * 2048 * sizeof(__hip_bfloat16));
    __hip_bfloat16* x_bf    = (__hip_bfloat16*)carve((size_t)Mpad * 256 * sizeof(__hip_bfloat16));
    __hip_bfloat16* pw_bf   = (__hip_bfloat16*)carve((size_t)256 * 512 * sizeof(__hip_bfloat16));
    __hip_bfloat16* w1t     = (__hip_bfloat16*)carve((size_t)2048 * 512 * sizeof(__hip_bfloat16));
    __hip_bfloat16* w2t     = (__hip_bfloat16*)carve((size_t)2048 * 2048 * sizeof(__hip_bfloat16));
    __hip_bfloat16* w3t     = (__hip_bfloat16*)carve((size_t)1024 * 2048 * sizeof(__hip_bfloat16));
    __hip_bfloat16* w_efft  = (__hip_bfloat16*)carve((size_t)2048 * 256 * sizeof(__hip_bfloat16));
    float* b_eff = (float*)carve((size_t)2048 * sizeof(float));
    float* b1s   = (float*)carve((size_t)2048 * sizeof(float));
    float* va    = (float*)carve((size_t)8 * 256 * sizeof(float));
    float* cvec  = (float*)carve((size_t)8 * sizeof(float));
    float* es  = (float*)carve((size_t)n * 4 * sizeof(float));
    float* ed  = (float*)carve((size_t)n * 4 * sizeof(float));
    uint2* rec = (uint2*)carve((size_t)Et * 4 * sizeof(uint2));   // {off,alpha} per (edge,head)
    int* deg = (int*)carve((size_t)2 * n * sizeof(int));   // deg + cur contiguous
    int* cur = deg + n;
    int* off = (int*)carve((size_t)(n + 1) * sizeof(int));
    int* csr = (int*)carve((size_t)Et * sizeof(int));
    __hip_bfloat16* z_bf = h_bf;   // layer-1 aggregated-x [Mpad,1024], overlays h_bf
    (void)ws_size; (void)n_in;

    // --- CSR build ---
    hipMemsetAsync(deg, 0, 2 * n * sizeof(int), stream);
    hipMemsetAsync(b_eff, 0, 2048 * sizeof(float), stream);
    hist_kernel<<<CDIV(Et, 256), 256, 0, stream>>>(ei, deg, E, Et);
    scan_kernel<<<1, 1024, 0, stream>>>(deg, off, n);
    scatter_kernel<<<CDIV(Et, 256), 256, 0, stream>>>(ei, off, cur, csr, E, Et);

    // --- weight prep (fused) ---
    const int t0 = (512 / 32) * (2048 / 32);            // 1024
    const int t1 = t0 + (2048 / 32) * (2048 / 32);      // +4096
    const int t2 = t1 + (2048 / 32) * (1024 / 32);      // +2048
    prep_t_kernel<<<t2, 256, 0, stream>>>(w1, w1t, w2, w2t, w3, w3t, t0, t1, t2);
    const int na4 = 256 * 512 / 4, nb4 = n * 256 / 4;
    cvt2_kernel<<<CDIV(na4 + nb4, 256), 256, 0, stream>>>(proj_w, pw_bf, na4, x, x_bf, nb4);

    // --- fold proj into layer 1: W_eff^T[2048,256]; b_eff = proj_b @ w1 ---
    gemm_bf16_kernel<<<8 * 2 * 2, 256, 0, stream>>>(
        w1t, pw_bf, nullptr, w_efft, 2048, 256, 512, 512, 0, 0, 16, 2, 2, 2);
    beff_kernel<<<dim3(2048 / 256, 512 / 64), 256, 0, stream>>>(proj_b, w1, b_eff, 2048);

    // --- layer-1 attention vectors + constants; b1s = b_eff + b1 ---
    va_kernel<<<9, 256, 0, stream>>>(w_efft, b_eff, as1, ad1, b1, va, cvec, b1s);

    // --- layer 1, aggregated in input space (fused softmax in agg1x) ---
    es1_kernel<<<n, 64, 0, stream>>>(x_bf, va, cvec, es, ed);
    agg1x_kernel<<<n, 256, 0, stream>>>(x_bf, es, ed, csr, off, z_bf);
    // act = ELU( z @ W_eff(per-head) + b_eff + b1 ): 128^2 kernel, 3 blk/CU
    gemm_bf16_kernel<<<8 * XT * 16, 256, 0, stream>>>(
        z_bf, w_efft, b1s, act_bf, n, 2048, 256, 1024, 256, 1, MB, 16, XT, 16);

    // --- layer 2 (H=4, concat): exact-256 big launch + exact-256 remainder ---
    gemm256_kernel<<<256, 512, 0, stream>>>(act_bf, w2t, h_bf, n, 2048, 2048, 40, 240);
    gemm128_kernel<<<256, 256, 0, stream>>>(act_bf, w2t, h_bf, n, 2048, 2048, 1, 0);
    esed_kernel<<<n, 4 * 64, 0, stream>>>(h_bf, as2, ad2, es, ed, 4);
    alpharec_kernel<4, 12><<<CDIV(n, 4), 256, 0, stream>>>(es, ed, csr, off, rec, n);
    agg2s_kernel<<<2048, 256, 0, stream>>>(h_bf, rec, off, b2, act_bf, n);

    // --- layer 3 (H=2): GEMM, records, direct-output aggregation ---
    gemm128_kernel<<<640, 256, 0, stream>>>(act_bf, w3t, h_bf, n, 1024, 2048, 0, 80);
    esed_kernel<<<n, 2 * 64, 0, stream>>>(h_bf, as3, ad3, es, ed, 2);
    alpharec_kernel<2, 11><<<CDIV(n, 4), 256, 0, stream>>>(es, ed, csr, off, rec, n);
    agg3s_kernel<<<2048, 256, 0, stream>>>(h_bf, rec, off, b3, (float*)d_out, n);
}

// Round 11
// 572.068 us; speedup vs baseline: 1.0169x; 1.0169x over previous
//
#include <hip/hip_runtime.h>
#include <hip/hip_bf16.h>
#include <math.h>

#define CDIV(a,b) (((a)+(b)-1)/(b))

typedef __bf16  bf16x8 __attribute__((ext_vector_type(8)));
typedef float   f32x4  __attribute__((ext_vector_type(4)));
typedef unsigned short u16x8 __attribute__((ext_vector_type(8)));
typedef unsigned short u16x4 __attribute__((ext_vector_type(4)));

__device__ __forceinline__ float bf2f(unsigned short u) {
    union { unsigned int i; float f; } x; x.i = ((unsigned int)u) << 16; return x.f;
}
__device__ __forceinline__ unsigned short f2bf(float f) {
    union { float f; unsigned int i; } x; x.f = f;
    unsigned int r = x.i + 0x7fff + ((x.i >> 16) & 1);   // RNE, finite inputs
    return (unsigned short)(r >> 16);
}

// Dword-wise bf16x8 -> f32x8: 4 shl + 4 and, guaranteed (R8 post-mortem).
__device__ __forceinline__ void bfx8_cvt(u16x8 v, float f[8]) {
    union { u16x8 v; unsigned d[4]; } u; u.v = v;
#pragma unroll
    for (int q = 0; q < 4; q++) {
        f[2*q]   = __uint_as_float(u.d[q] << 16);
        f[2*q+1] = __uint_as_float(u.d[q] & 0xffff0000u);
    }
}
__device__ __forceinline__ void bfx4_cvt(u16x4 v, float f[4]) {
    union { u16x4 v; unsigned d[2]; } u; u.v = v;
#pragma unroll
    for (int q = 0; q < 2; q++) {
        f[2*q]   = __uint_as_float(u.d[q] << 16);
        f[2*q+1] = __uint_as_float(u.d[q] & 0xffff0000u);
    }
}
// ELU with hardware exp: error < 1.2e-7 vs expm1f on v<=0, under bf16 rounding.
__device__ __forceinline__ float elu_fast(float v) {
    return (v > 0.f) ? v : (__expf(v) - 1.f);
}

// ---------------------------------------------------------------------------
// CSR build (by destination node). Edges = [E graph edges] + [n self-loops].
// ---------------------------------------------------------------------------
__global__ void hist_kernel(const int* __restrict__ ei, int* __restrict__ deg,
                            int E, int Et) {
    int e = blockIdx.x * blockDim.x + threadIdx.x;
    if (e >= Et) return;
    int d = (e < E) ? ei[E + e] : (e - E);
    atomicAdd(&deg[d], 1);
}

// Single-block exclusive scan, wave-shuffle based.
__global__ void scan_kernel(const int* __restrict__ deg, int* __restrict__ off, int n) {
    __shared__ int wsum[16];
    __shared__ int carry_s;
    int t = threadIdx.x, lane = t & 63, wv = t >> 6;
    if (t == 0) carry_s = 0;
    __syncthreads();
    for (int base = 0; base < n; base += 1024) {
        int v = (base + t < n) ? deg[base + t] : 0;
        int x = v;
#pragma unroll
        for (int o = 1; o < 64; o <<= 1) {
            int y = __shfl_up(x, o);
            if (lane >= o) x += y;
        }
        if (lane == 63) wsum[wv] = x;
        __syncthreads();
        if (wv == 0 && lane < 16) {
            int s = wsum[lane];
#pragma unroll
            for (int o = 1; o < 16; o <<= 1) {
                int y = __shfl_up(s, o);
                if (lane >= o) s += y;
            }
            wsum[lane] = s;
        }
        __syncthreads();
        int wprev = (wv == 0) ? 0 : wsum[wv - 1];
        int incl = carry_s + wprev + x;
        if (base + t < n) off[base + t] = incl - v;
        __syncthreads();
        if (t == 1023) carry_s = incl;
        __syncthreads();
    }
    if (t == 0) off[n] = carry_s;
}

__global__ void scatter_kernel(const int* __restrict__ ei, const int* __restrict__ off,
                               int* __restrict__ cur, int* __restrict__ csr,
                               int E, int Et) {
    int e = blockIdx.x * blockDim.x + threadIdx.x;
    if (e >= Et) return;
    int s, d;
    if (e < E) { s = ei[e]; d = ei[E + e]; } else { s = e - E; d = s; }
    int pos = off[d] + atomicAdd(&cur[d], 1);
    csr[pos] = s;
}

// ---------------------------------------------------------------------------
// Fused weight transpose+cvt: 3 jobs in one launch, 32x32 tiles.
// ---------------------------------------------------------------------------
__global__ void prep_t_kernel(const float* __restrict__ wa, __hip_bfloat16* __restrict__ wta,
                              const float* __restrict__ wb, __hip_bfloat16* __restrict__ wtb,
                              const float* __restrict__ wc, __hip_bfloat16* __restrict__ wtc,
                              int t0, int t1, int t2) {
    __shared__ float tile[32][33];
    int bid = blockIdx.x;
    const float* w; __hip_bfloat16* wt; int K, N, r;
    if (bid < t0)      { w = wa; wt = wta; K = 512;  N = 2048; r = bid; }
    else if (bid < t1) { w = wb; wt = wtb; K = 2048; N = 2048; r = bid - t0; }
    else               { w = wc; wt = wtc; K = 2048; N = 1024; r = bid - t1; }
    (void)t2;
    int kt = K >> 5;
    int kb = (r % kt) * 32, nb = (r / kt) * 32;
    int tx = threadIdx.x & 31, ty = threadIdx.x >> 5;
    for (int i = ty; i < 32; i += 8)
        tile[i][tx] = w[(size_t)(kb + i) * N + nb + tx];
    __syncthreads();
    for (int i = ty; i < 32; i += 8)
        wt[(size_t)(nb + i) * K + kb + tx] = __float2bfloat16(tile[tx][i]);
}

// Fused fp32->bf16 convert of proj_w then x (both sizes %4 == 0).
__global__ void cvt2_kernel(const float* __restrict__ a, __hip_bfloat16* __restrict__ ao,
                            int na4,
                            const float* __restrict__ b, __hip_bfloat16* __restrict__ bo,
                            int nb4) {
    int i = blockIdx.x * blockDim.x + threadIdx.x;
    const float* src; __hip_bfloat16* dst; int idx;
    if (i < na4) { src = a; dst = ao; idx = i * 4; }
    else if (i < na4 + nb4) { src = b; dst = bo; idx = (i - na4) * 4; }
    else return;
    float4 v = *(const float4*)(src + idx);
    dst[idx + 0] = __float2bfloat16(v.x);
    dst[idx + 1] = __float2bfloat16(v.y);
    dst[idx + 2] = __float2bfloat16(v.z);
    dst[idx + 3] = __float2bfloat16(v.w);
}

// b_eff[j] += partial over k-chunk of proj_b[k]*w1[k][j] (k-split, unrolled).
__global__ void beff_kernel(const float* __restrict__ pb, const float* __restrict__ w1,
                            float* __restrict__ beff, int N) {
    int j  = blockIdx.x * 256 + threadIdx.x;
    int k0 = blockIdx.y * 64;
    float s = 0.f;
#pragma unroll
    for (int k = 0; k < 64; k++)
        s = fmaf(pb[k0 + k], w1[(size_t)(k0 + k) * N + j], s);
    atomicAdd(&beff[j], s);
}

// ---------------------------------------------------------------------------
// va[j][256] = W_eff[:, head-block j] @ a_vec   (j<4: a_src head j; j>=4: a_dst)
// cvec[j] = b_eff[head-block] . a_vec ;  block 8 computes b1s = b_eff + b1.
// ---------------------------------------------------------------------------
__global__ void va_kernel(const __hip_bfloat16* __restrict__ w_efft,
                          const float* __restrict__ b_eff,
                          const float* __restrict__ as1, const float* __restrict__ ad1,
                          const float* __restrict__ b1,
                          float* __restrict__ va, float* __restrict__ cvec,
                          float* __restrict__ b1s) {
    int j = blockIdx.x, t = threadIdx.x;
    if (j == 8) {
        for (int i = t; i < 2048; i += 256) b1s[i] = b_eff[i] + b1[i];
        return;
    }
    int h = j & 3;
    const float* a = ((j < 4) ? as1 : ad1) + h * 512;
    __shared__ float aLDS[512];
    __shared__ float red[256];
    for (int c = t; c < 512; c += 256) aLDS[c] = a[c];
    __syncthreads();
    float acc = 0.f;
    const unsigned short* wb = (const unsigned short*)w_efft + (size_t)h * 512 * 256 + t;
    for (int c = 0; c < 512; c++)
        acc = fmaf(aLDS[c], bf2f(wb[(size_t)c * 256]), acc);
    va[j * 256 + t] = acc;
    float cp = b_eff[h * 512 + t] * aLDS[t] + b_eff[h * 512 + 256 + t] * aLDS[256 + t];
    red[t] = cp;
    __syncthreads();
    for (int s = 128; s > 0; s >>= 1) {
        if (t < s) red[t] += red[t + s];
        __syncthreads();
    }
    if (t == 0) cvec[j] = red[0];
}

// ---------------------------------------------------------------------------
// es1/ed1: es[node][h] = x_bf[node] . va[h] + cvec[h]  (one wave per node).
// ---------------------------------------------------------------------------
__global__ void es1_kernel(const __hip_bfloat16* __restrict__ x_bf,
                           const float* __restrict__ va, const float* __restrict__ cvec,
                           float* __restrict__ es, float* __restrict__ ed) {
    int node = blockIdx.x, l = threadIdx.x;
    u16x4 xv = *(const u16x4*)((const unsigned short*)x_bf + (size_t)node * 256 + l * 4);
    float xf[4];
    bfx4_cvt(xv, xf);
    float dot[8];
#pragma unroll
    for (int j = 0; j < 8; j++) {
        float4 v = *(const float4*)(va + j * 256 + l * 4);
        dot[j] = xf[0] * v.x + xf[1] * v.y + xf[2] * v.z + xf[3] * v.w;
    }
#pragma unroll
    for (int j = 0; j < 8; j++)
        for (int o = 32; o; o >>= 1) dot[j] += __shfl_down(dot[j], o);
    if (l == 0) {
#pragma unroll
        for (int h = 0; h < 4; h++) {
            es[node * 4 + h] = dot[h] + cvec[h];
            ed[node * 4 + h] = dot[4 + h] + cvec[4 + h];
        }
    }
}

// ---------------------------------------------------------------------------
// alpha4: normalized attention weights per edge (all 4 heads as float4),
// one wave per dst. al4[i] = {alpha_h0..alpha_h3} in CSR position i.
// (R10 post-mortem: fusing this into agg1x recomputes exp 2x per edge in the
// latency-bound per-dst path -- separate streaming pass is cheaper.)
// ---------------------------------------------------------------------------
__global__ __launch_bounds__(256) void alpha4_kernel(
    const float* __restrict__ es, const float* __restrict__ ed,
    const int* __restrict__ csr, const int* __restrict__ off,
    float4* __restrict__ al4, int n)
{
    int d = blockIdx.x * 4 + (threadIdx.x >> 6);
    if (d >= n) return;
    int lane = threadIdx.x & 63;
    int beg = off[d], end = off[d + 1];
    float edd[4], den[4];
#pragma unroll
    for (int h = 0; h < 4; h++) { edd[h] = ed[d * 4 + h]; den[h] = 0.f; }
    for (int i = beg + lane; i < end; i += 64) {
        int s = csr[i];
#pragma unroll
        for (int h = 0; h < 4; h++) {
            float e = es[s * 4 + h] + edd[h];
            e = (e > 0.f) ? e : 0.2f * e;
            den[h] += __expf(e);
        }
    }
#pragma unroll
    for (int h = 0; h < 4; h++) {
        for (int o = 32; o; o >>= 1) den[h] += __shfl_down(den[h], o);
        den[h] = __shfl(den[h], 0);
        den[h] = 1.f / den[h];
    }
    for (int i = beg + lane; i < end; i += 64) {
        int s = csr[i];
        float a[4];
#pragma unroll
        for (int h = 0; h < 4; h++) {
            float e = es[s * 4 + h] + edd[h];
            e = (e > 0.f) ? e : 0.2f * e;
            a[h] = __expf(e) * den[h];
        }
        al4[i] = make_float4(a[0], a[1], a[2], a[3]);
    }
}

// ---------------------------------------------------------------------------
// Layer-1 aggregation v2 in INPUT space (256 ch, 4 heads): one block per dst,
// 4 waves process 4 edges concurrently, u16x4 vector gathers (512B/wave =
// full x row), alpha precomputed (al4), 16KB-LDS cross-wave reduce.
// ---------------------------------------------------------------------------
__global__ __launch_bounds__(256) void agg1x_kernel(
    const __hip_bfloat16* __restrict__ x_bf, const float4* __restrict__ al4,
    const int* __restrict__ csr, const int* __restrict__ off,
    __hip_bfloat16* __restrict__ z)
{
    __shared__ float red[4][1024];
    int d = blockIdx.x, t = threadIdx.x;
    int w = t >> 6, l = t & 63;
    int c0 = l * 4;
    int beg = off[d], end = off[d + 1];
    float acc[4][4] = {};   // [k (ch)][h (head)]
    const unsigned short* xb = (const unsigned short*)x_bf;

    for (int i = beg + w; i < end; i += 4) {
        int s = csr[i];
        float4 a = al4[i];
        u16x4 xv = *(const u16x4*)(xb + (size_t)s * 256 + c0);
        float xf[4];
        bfx4_cvt(xv, xf);
#pragma unroll
        for (int k = 0; k < 4; k++) {
            acc[k][0] = fmaf(a.x, xf[k], acc[k][0]);
            acc[k][1] = fmaf(a.y, xf[k], acc[k][1]);
            acc[k][2] = fmaf(a.z, xf[k], acc[k][2]);
            acc[k][3] = fmaf(a.w, xf[k], acc[k][3]);
        }
    }
#pragma unroll
    for (int h = 0; h < 4; h++)
#pragma unroll
        for (int k = 0; k < 4; k++)
            red[w][h * 256 + c0 + k] = acc[k][h];
    __syncthreads();
    unsigned short* zb = (unsigned short*)z + (size_t)d * 1024;
#pragma unroll
    for (int q = 0; q < 4; q++) {
        int m = t + q * 256;
        float v = red[0][m] + red[1][m] + red[2][m] + red[3][m];
        zb[m] = f2bf(v);
    }
}

// ---------------------------------------------------------------------------
// bf16 MFMA GEMM: Cb[M,N] = bf16(act( A[M,K(lda)] @ BT[N,K]^T + bias ))
// 128x128 tile, BK=32, 256 threads (4 waves), 16x16x32 MFMA. 3 blk/CU.
// Used for the fold-GEMM and the L1 GEMM (K=256: shallow-K wants small tiles
// + multi-block-per-CU occupancy -- R7 post-mortem).
// ---------------------------------------------------------------------------
__device__ __forceinline__ void gload16(void* lds, const void* g) {
    __builtin_amdgcn_global_load_lds(
        (const __attribute__((address_space(1))) void*)g,
        (__attribute__((address_space(3))) void*)lds, 16, 0, 0);
}

__global__ __launch_bounds__(256) void gemm_bf16_kernel(
    const __hip_bfloat16* __restrict__ A,
    const __hip_bfloat16* __restrict__ BT,
    const float* __restrict__ bias,
    __hip_bfloat16* __restrict__ Cb,
    int M, int N, int K, int lda, int hko, int do_elu,
    int MB, int NB, int XT, int NBH)
{
    __shared__ __align__(16) __hip_bfloat16 As[128 * 32];
    __shared__ __align__(16) __hip_bfloat16 Bs[128 * 32];

    const int bid  = blockIdx.x;
    const int xcd  = bid & 7;
    const int slot = bid >> 3;
    const int per_yh = XT * NBH;
    const int yh    = slot / per_yh;
    const int rem   = slot - yh * per_yh;
    const int x_sub = rem / NBH;
    const int ys    = rem - x_sub * NBH;
    const int yb    = yh * NBH + ys;
    const int xb    = xcd * XT + x_sub;
    if (xb >= MB || yb >= NB) return;

    const int tid = threadIdx.x;
    const int m0 = xb * 128, n0 = yb * 128;
    const int w = tid >> 6, l = tid & 63;
    const int wm = (w & 1) * 64, wn = (w >> 1) * 64;
    const int lm = l & 15, lq = l >> 4;

    f32x4 acc[4][4] = {};

    const int arow = tid >> 2;
    const int acol = (tid & 3) * 8;
    const __hip_bfloat16* Ag = A + (size_t)(m0 + arow) * lda + acol + (n0 >> 9) * hko;
    const __hip_bfloat16* Bg = BT + (size_t)(n0 + arow) * K + acol;
    char* AsW = (char*)As + (w << 10);
    char* BsW = (char*)Bs + (w << 10);

    for (int k0 = 0; k0 < K; k0 += 32) {
        gload16(AsW,        Ag + k0);
        gload16(AsW + 4096, Ag + (size_t)64 * lda + k0);
        gload16(BsW,        Bg + k0);
        gload16(BsW + 4096, Bg + (size_t)64 * K + k0);
        __syncthreads();
        bf16x8 af[4], bfr[4];
#pragma unroll
        for (int i = 0; i < 4; i++)
            af[i] = *(const bf16x8*)(As + (wm + i * 16 + lm) * 32 + lq * 8);
#pragma unroll
        for (int j = 0; j < 4; j++)
            bfr[j] = *(const bf16x8*)(Bs + (wn + j * 16 + lm) * 32 + lq * 8);
#pragma unroll
        for (int i = 0; i < 4; i++)
#pragma unroll
            for (int j = 0; j < 4; j++)
                acc[i][j] = __builtin_amdgcn_mfma_f32_16x16x32_bf16(
                    af[i], bfr[j], acc[i][j], 0, 0, 0);
        __syncthreads();
    }

#pragma unroll
    for (int i = 0; i < 4; i++) {
        int rb = m0 + wm + i * 16 + lq * 4;
#pragma unroll
        for (int r = 0; r < 4; r++) {
            int row = rb + r;
            if (row >= M) continue;
#pragma unroll
            for (int j = 0; j < 4; j++) {
                int col = n0 + wn + j * 16 + lm;
                float v = acc[i][j][r];
                if (bias) v += bias[col];
                if (do_elu) v = elu_fast(v);
                Cb[(size_t)row * N + col] = __float2bfloat16(v);
            }
        }
    }
}

// ---------------------------------------------------------------------------
// 256x256 8-phase bf16 GEMM (T2+T3+T4+T5 template, plain HIP). K>=1024 only.
//   slot < nfull  -> (mt = slot % MT, ntl = slot / MT)
//   slot >= nfull -> (ntl = nfull/MT, mt = nfull%MT + slot - nfull)
// ---------------------------------------------------------------------------
__global__ __launch_bounds__(512, 2) void gemm256_kernel(
    const __hip_bfloat16* __restrict__ A,
    const __hip_bfloat16* __restrict__ BT,
    __hip_bfloat16* __restrict__ Cb,
    int M, int N, int K, int MT, int nfull)
{
    __shared__ __align__(16) char smem[131072];
    const int NT = K >> 6;

    const int cpx  = gridDim.x >> 3;
    const int bid  = blockIdx.x;
    const int slot = (bid & 7) * cpx + (bid >> 3);
    int mt, ntl;
    if (slot < nfull) { mt = slot % MT; ntl = slot / MT; }
    else              { ntl = nfull / MT; mt = (nfull % MT) + (slot - nfull); }
    const int m0 = mt << 8, n0 = ntl << 8;

    const int tid = threadIdx.x;
    const int w  = tid >> 6, l = tid & 63;
    const int wr = w >> 2, wc = w & 3;        // 2 M-waves x 4 N-waves
    const int lm = l & 15, lq = l >> 4;

    // --- staging constants (linear LDS dest, inverse-swizzled global src) ---
    const int srow = tid >> 3;                           // 0..63
    const int scol = ((l & 7) << 3) ^ ((l >> 3) << 3);   // bf16 col, 16B-aligned
    const __hip_bfloat16* As0 = A  + (size_t)(m0 + srow) * K + scol;
    const __hip_bfloat16* Bs0 = BT + (size_t)(n0 + srow) * K + scol;
    const size_t rs64  = (size_t)64  * K;
    const size_t rs128 = (size_t)128 * K;
    char* const stA = smem +          ((size_t)w << 10);
    char* const stB = smem + 65536 +  ((size_t)w << 10);

    auto STAGE_A = [&](int par, int hf, int tt) {
        char* d = stA + (((par << 1) | hf) << 14);
        const __hip_bfloat16* s = As0 + (size_t)hf * rs128 + (tt << 6);
        gload16(d,        s);
        gload16(d + 8192, s + rs64);
    };
    auto STAGE_B = [&](int par, int hf, int tt) {
        char* d = stB + (((par << 1) | hf) << 14);
        const __hip_bfloat16* s = Bs0 + (size_t)hf * rs128 + (tt << 6);
        gload16(d,        s);
        gload16(d + 8192, s + rs64);
    };

    // --- ds_read constants (swizzled) ---
    const int roff = lm << 7;                 // row-within-16 block * 128B
    const int xm   = (lm & 7) << 4;
    const int off0 = (lq << 4) ^ xm;          // kk = 0
    const int off1 = off0 ^ 64;               // kk = 1
    const int bsel = 65536 + ((wc & 1) << 13);

    f32x4  acc[8][4] = {};
    bf16x8 af[8][2];
    bf16x8 bfr[2][2];

    // --- prologue: half-tiles h=0..5 ---
    STAGE_A(0, 0, 0); STAGE_A(0, 1, 0);
    STAGE_B(0, 0, 0); STAGE_B(0, 1, 0);
    STAGE_A(1, 0, 1); STAGE_A(1, 1, 1);
    asm volatile("s_waitcnt vmcnt(4)" ::: "memory");
    __builtin_amdgcn_s_barrier();

    for (int t = 0; t < NT; ++t) {
        const int par = t & 1;
        const char* aS = smem + (((par << 1) | wr)        << 14) + roff;
        const char* bS = smem + (((par << 1) | (wc >> 1)) << 14) + bsel + roff;

        // ===== phase 0 : Q1 (Mlo x Nlo) =====
#pragma unroll
        for (int i = 0; i < 4; ++i) {
            af[i][0] = *(const bf16x8*)(aS + i * 2048 + off0);
            af[i][1] = *(const bf16x8*)(aS + i * 2048 + off1);
        }
#pragma unroll
        for (int j = 0; j < 2; ++j) {
            bfr[j][0] = *(const bf16x8*)(bS + j * 2048 + off0);
            bfr[j][1] = *(const bf16x8*)(bS + j * 2048 + off1);
        }
        if (t + 1 < NT) STAGE_B(par ^ 1, 0, t + 1);
        __builtin_amdgcn_s_barrier();
        asm volatile("s_waitcnt lgkmcnt(0)" ::: "memory");
        __builtin_amdgcn_sched_barrier(0);
        __builtin_amdgcn_s_setprio(1);
#pragma unroll
        for (int i = 0; i < 4; ++i)
#pragma unroll
            for (int j = 0; j < 2; ++j) {
                acc[i][j] = __builtin_amdgcn_mfma_f32_16x16x32_bf16(af[i][0], bfr[j][0], acc[i][j], 0, 0, 0);
                acc[i][j] = __builtin_amdgcn_mfma_f32_16x16x32_bf16(af[i][1], bfr[j][1], acc[i][j], 0, 0, 0);
            }
        __builtin_amdgcn_s_setprio(0);
        __builtin_amdgcn_s_barrier();

        // ===== phase 1 : Q2 (Mhi x Nlo) =====
#pragma unroll
        for (int i = 4; i < 8; ++i) {
            af[i][0] = *(const bf16x8*)(aS + i * 2048 + off0);
            af[i][1] = *(const bf16x8*)(aS + i * 2048 + off1);
        }
        if (t + 1 < NT) STAGE_B(par ^ 1, 1, t + 1);
        __builtin_amdgcn_s_barrier();
        asm volatile("s_waitcnt lgkmcnt(0)" ::: "memory");
        __builtin_amdgcn_sched_barrier(0);
        __builtin_amdgcn_s_setprio(1);
#pragma unroll
        for (int i = 4; i < 8; ++i)
#pragma unroll
            for (int j = 0; j < 2; ++j) {
                acc[i][j] = __builtin_amdgcn_mfma_f32_16x16x32_bf16(af[i][0], bfr[j][0], acc[i][j], 0, 0, 0);
                acc[i][j] = __builtin_amdgcn_mfma_f32_16x16x32_bf16(af[i][1], bfr[j][1], acc[i][j], 0, 0, 0);
            }
        __builtin_amdgcn_s_setprio(0);
        __builtin_amdgcn_s_barrier();

        // ===== phase 2 : Q3 (Mlo x Nhi) =====
#pragma unroll
        for (int j = 0; j < 2; ++j) {
            bfr[j][0] = *(const bf16x8*)(bS + (j + 2) * 2048 + off0);
            bfr[j][1] = *(const bf16x8*)(bS + (j + 2) * 2048 + off1);
        }
        if (t + 2 < NT) STAGE_A(par, 0, t + 2);
        __builtin_amdgcn_s_barrier();
        asm volatile("s_waitcnt lgkmcnt(0)" ::: "memory");
        __builtin_amdgcn_sched_barrier(0);
        __builtin_amdgcn_s_setprio(1);
#pragma unroll
        for (int i = 0; i < 4; ++i)
#pragma unroll
            for (int j = 0; j < 2; ++j) {
                acc[i][j + 2] = __builtin_amdgcn_mfma_f32_16x16x32_bf16(af[i][0], bfr[j][0], acc[i][j + 2], 0, 0, 0);
                acc[i][j + 2] = __builtin_amdgcn_mfma_f32_16x16x32_bf16(af[i][1], bfr[j][1], acc[i][j + 2], 0, 0, 0);
            }
        __builtin_amdgcn_s_setprio(0);
        __builtin_amdgcn_s_barrier();

        // ===== phase 3 : Q4 (Mhi x Nhi) =====
        if (t + 2 < NT) STAGE_A(par, 1, t + 2);
        __builtin_amdgcn_s_barrier();
        __builtin_amdgcn_sched_barrier(0);
        __builtin_amdgcn_s_setprio(1);
#pragma unroll
        for (int i = 4; i < 8; ++i)
#pragma unroll
            for (int j = 0; j < 2; ++j) {
                acc[i][j + 2] = __builtin_amdgcn_mfma_f32_16x16x32_bf16(af[i][0], bfr[j][0], acc[i][j + 2], 0, 0, 0);
                acc[i][j + 2] = __builtin_amdgcn_mfma_f32_16x16x32_bf16(af[i][1], bfr[j][1], acc[i][j + 2], 0, 0, 0);
            }
        __builtin_amdgcn_s_setprio(0);
        if (t + 2 < NT)      { asm volatile("s_waitcnt vmcnt(4)" ::: "memory"); }
        else if (t + 1 < NT) { asm volatile("s_waitcnt vmcnt(0)" ::: "memory"); }
        __builtin_amdgcn_s_barrier();
    }

    // --- epilogue: C write (row-guarded; pad rows discarded) ---
#pragma unroll
    for (int i = 0; i < 8; ++i) {
        int rb = m0 + wr * 128 + i * 16 + lq * 4;
#pragma unroll
        for (int r = 0; r < 4; ++r) {
            int row = rb + r;
            if (row >= M) continue;
#pragma unroll
            for (int j = 0; j < 4; ++j) {
                int col = n0 + wc * 64 + j * 16 + lm;
                Cb[(size_t)row * N + col] = __float2bfloat16(acc[i][j][r]);
            }
        }
    }
}

// ---------------------------------------------------------------------------
// 128x128 bf16 GEMM, BK=64, 256 thr (4 waves 2x2), 64 KiB dbuf LDS (2 blk/CU).
// mode 0: r = slot % RT, c = slot / RT          (layer 3: grid 640, RT=80)
// mode 1: layer-2 remainder of the 40x8 256-tile space after 256 big tiles.
// ---------------------------------------------------------------------------
__global__ __launch_bounds__(256, 2) void gemm128_kernel(
    const __hip_bfloat16* __restrict__ A,
    const __hip_bfloat16* __restrict__ BT,
    __hip_bfloat16* __restrict__ Cb,
    int M, int N, int K, int mode, int RT)
{
    __shared__ __align__(16) char smem[65536];
    const int NT = K >> 6;

    const int cpx  = gridDim.x >> 3;
    const int bid  = blockIdx.x;
    const int slot = (bid & 7) * cpx + (bid >> 3);
    int r, c;
    if (mode == 0) { r = slot % RT; c = slot / RT; }
    else {
        if (slot < 96) { c = 12 + slot / 48; r = 32 + slot % 48; }
        else           { int u = slot - 96; c = 14 + u / 80; r = u % 80; }
    }
    const int m0 = r << 7, n0 = c << 7;

    const int tid = threadIdx.x;
    const int w = tid >> 6, l = tid & 63;
    const int wm = (w & 1) << 6, wn = (w >> 1) << 6;
    const int lm = l & 15, lq = l >> 4;

    // staging: 16 KiB/operand/tile = 4 sweeps of 4 KiB (32 rows each)
    const int srow = tid >> 3;                                  // 0..31
    const int scol = (((tid & 7) ^ ((tid >> 3) & 7)) << 3);     // bf16 col
    const __hip_bfloat16* Ag = A  + (size_t)(m0 + srow) * K + scol;
    const __hip_bfloat16* Bg = BT + (size_t)(n0 + srow) * K + scol;
    const size_t rs32 = (size_t)32 * K;
    char* const dA = smem +         ((size_t)w << 10);
    char* const dB = smem + 16384 + ((size_t)w << 10);

    auto STAGE = [&](int par, int tt) {
        char* pa = dA + (par << 15);
        char* pb = dB + (par << 15);
        const __hip_bfloat16* sa = Ag + (tt << 6);
        const __hip_bfloat16* sb = Bg + (tt << 6);
#pragma unroll
        for (int s = 0; s < 4; ++s) {
            gload16(pa + (s << 12), sa + (size_t)s * rs32);
            gload16(pb + (s << 12), sb + (size_t)s * rs32);
        }
    };

    const int roff = lm << 7;
    const int off0 = (lq << 4) ^ ((lm & 7) << 4);
    const int off1 = off0 ^ 64;

    f32x4 acc[4][4] = {};

    STAGE(0, 0);
    asm volatile("s_waitcnt vmcnt(0)" ::: "memory");
    __builtin_amdgcn_s_barrier();

    for (int t = 0; t < NT; ++t) {
        const int par = t & 1;
        if (t + 1 < NT) STAGE(par ^ 1, t + 1);
        const char* aS = smem + (par << 15) +         wm * 128 + roff;
        const char* bS = smem + (par << 15) + 16384 + wn * 128 + roff;
        bf16x8 af[4][2], bfr[4][2];
#pragma unroll
        for (int i = 0; i < 4; ++i) {
            af[i][0]  = *(const bf16x8*)(aS + i * 2048 + off0);
            af[i][1]  = *(const bf16x8*)(aS + i * 2048 + off1);
            bfr[i][0] = *(const bf16x8*)(bS + i * 2048 + off0);
            bfr[i][1] = *(const bf16x8*)(bS + i * 2048 + off1);
        }
        asm volatile("s_waitcnt lgkmcnt(0)" ::: "memory");
        __builtin_amdgcn_sched_barrier(0);
        __builtin_amdgcn_s_setprio(1);
#pragma unroll
        for (int i = 0; i < 4; ++i)
#pragma unroll
            for (int j = 0; j < 4; ++j) {
                acc[i][j] = __builtin_amdgcn_mfma_f32_16x16x32_bf16(af[i][0], bfr[j][0], acc[i][j], 0, 0, 0);
                acc[i][j] = __builtin_amdgcn_mfma_f32_16x16x32_bf16(af[i][1], bfr[j][1], acc[i][j], 0, 0, 0);
            }
        __builtin_amdgcn_s_setprio(0);
        if (t + 1 < NT) asm volatile("s_waitcnt vmcnt(0)" ::: "memory");
        __builtin_amdgcn_s_barrier();
    }

#pragma unroll
    for (int i = 0; i < 4; ++i) {
        int rb = m0 + wm + i * 16 + lq * 4;
#pragma unroll
        for (int r2 = 0; r2 < 4; ++r2) {
            int row = rb + r2;
            if (row >= M) continue;
#pragma unroll
            for (int j = 0; j < 4; ++j) {
                int col = n0 + wn + j * 16 + lm;
                Cb[(size_t)row * N + col] = __float2bfloat16(acc[i][j][r2]);
            }
        }
    }
}

// ---------------------------------------------------------------------------
// es/ed: per-node per-head dot with a_src/a_dst (h in bf16). One wave/head.
// ---------------------------------------------------------------------------
__global__ void esed_kernel(const __hip_bfloat16* __restrict__ h,
                            const float* __restrict__ a_src,
                            const float* __restrict__ a_dst,
                            float* __restrict__ es, float* __restrict__ ed, int H) {
    int nidx = blockIdx.x;
    int t = threadIdx.x;
    int head = t >> 6, lane = t & 63;
    const unsigned short* hp =
        (const unsigned short*)h + (size_t)nidx * H * 512 + head * 512 + lane * 8;
    const float* sp = a_src + head * 512 + lane * 8;
    const float* dp = a_dst + head * 512 + lane * 8;
    u16x8 hv = *(const u16x8*)hp;
    float4 s0 = *(const float4*)sp, s1 = *(const float4*)(sp + 4);
    float4 d0 = *(const float4*)dp, d1 = *(const float4*)(dp + 4);
    float hf[8];
    bfx8_cvt(hv, hf);
    float s = hf[0]*s0.x + hf[1]*s0.y + hf[2]*s0.z + hf[3]*s0.w
            + hf[4]*s1.x + hf[5]*s1.y + hf[6]*s1.z + hf[7]*s1.w;
    float d = hf[0]*d0.x + hf[1]*d0.y + hf[2]*d0.z + hf[3]*d0.w
            + hf[4]*d1.x + hf[5]*d1.y + hf[6]*d1.z + hf[7]*d1.w;
    for (int o = 32; o; o >>= 1) { s += __shfl_down(s, o); d += __shfl_down(d, o); }
    if (lane == 0) { es[nidx * H + head] = s; ed[nidx * H + head] = d; }
}

// ---------------------------------------------------------------------------
// alpharec: per (edge, head) record {row_byte_offset = src << SHIFT, alpha}.
// One wave per dst; alpha = exp(leaky(es+ed)) / den.
// ---------------------------------------------------------------------------
template<int H, int SHIFT>
__global__ __launch_bounds__(256) void alpharec_kernel(
    const float* __restrict__ es, const float* __restrict__ ed,
    const int* __restrict__ csr, const int* __restrict__ off,
    uint2* __restrict__ rec, int n)
{
    int d = blockIdx.x * 4 + (threadIdx.x >> 6);
    if (d >= n) return;
    int lane = threadIdx.x & 63;
    int beg = off[d], end = off[d + 1];
    float edd[H], den[H];
#pragma unroll
    for (int h = 0; h < H; h++) { edd[h] = ed[d * H + h]; den[h] = 0.f; }
    for (int i = beg + lane; i < end; i += 64) {
        int s = csr[i];
#pragma unroll
        for (int h = 0; h < H; h++) {
            float e = es[s * H + h] + edd[h];
            e = (e > 0.f) ? e : 0.2f * e;
            den[h] += __expf(e);
        }
    }
#pragma unroll
    for (int h = 0; h < H; h++) {
        for (int o = 32; o; o >>= 1) den[h] += __shfl_down(den[h], o);
        den[h] = __shfl(den[h], 0);
        den[h] = 1.f / den[h];
    }
    for (int i = beg + lane; i < end; i += 64) {
        int s = csr[i];
        unsigned obytes = ((unsigned)s) << SHIFT;
#pragma unroll
        for (int h = 0; h < H; h++) {
            float e = es[s * H + h] + edd[h];
            e = (e > 0.f) ? e : 0.2f * e;
            float a = __expf(e) * den[h];
            rec[(size_t)i * H + h] = make_uint2(obytes, __float_as_uint(a));
        }
    }
}

// ---------------------------------------------------------------------------
// Layer-2 aggregation v3: XCD-pinned 256-ch slices (L2-resident working set),
// half-wave u16x8 gathers, precomputed {offset,alpha} records, dword cvt.
// ---------------------------------------------------------------------------
__global__ __launch_bounds__(256) void agg2s_kernel(
    const __hip_bfloat16* __restrict__ h, const uint2* __restrict__ rec,
    const int* __restrict__ off, const float* __restrict__ bias,
    __hip_bfloat16* __restrict__ outB, int n)
{
    const int bid   = blockIdx.x;
    const int slice = bid & 7;
    const int head  = slice >> 1;
    const int wvs   = (bid >> 3) * 4 + (threadIdx.x >> 6);   // 0..1023
    const int lane  = threadIdx.x & 63;
    const int half  = lane >> 5;
    const int c0    = slice * 256 + (lane & 31) * 8;
    const unsigned c0b = (unsigned)c0 * 2;                   // byte offset in row
    const char* hb = (const char*)h;
    float bv[8];
#pragma unroll
    for (int k = 0; k < 8; k++) bv[k] = bias[c0 + k];

    for (int d = wvs; d < n; d += 1024) {
        int beg = off[d], end = off[d + 1];
        float acc[8] = {0.f, 0.f, 0.f, 0.f, 0.f, 0.f, 0.f, 0.f};
        int i = beg + half;
        for (; i + 2 < end; i += 4) {        // 2 edges per half per iter
            uint2 r0 = rec[i * 4 + head];
            uint2 r1 = rec[(i + 2) * 4 + head];
            u16x8 v0 = *(const u16x8*)(hb + (size_t)(r0.x + c0b));
            u16x8 v1 = *(const u16x8*)(hb + (size_t)(r1.x + c0b));
            float a0 = __uint_as_float(r0.y);
            float a1 = __uint_as_float(r1.y);
            float f0[8], f1[8];
            bfx8_cvt(v0, f0);
            bfx8_cvt(v1, f1);
#pragma unroll
            for (int k = 0; k < 8; k++) acc[k] = fmaf(a0, f0[k], acc[k]);
#pragma unroll
            for (int k = 0; k < 8; k++) acc[k] = fmaf(a1, f1[k], acc[k]);
        }
        for (; i < end; i += 2) {
            uint2 r0 = rec[i * 4 + head];
            u16x8 v0 = *(const u16x8*)(hb + (size_t)(r0.x + c0b));
            float a0 = __uint_as_float(r0.y);
            float f0[8];
            bfx8_cvt(v0, f0);
#pragma unroll
            for (int k = 0; k < 8; k++) acc[k] = fmaf(a0, f0[k], acc[k]);
        }
#pragma unroll
        for (int k = 0; k < 8; k++) acc[k] += __shfl_xor(acc[k], 32);
        if (half == 0) {
            u16x8 ov;
#pragma unroll
            for (int k = 0; k < 8; k++) {
                float v = elu_fast(acc[k] + bv[k]);
                ov[k] = f2bf(v);
            }
            *(u16x8*)((unsigned short*)outB + (size_t)d * 2048 + c0) = ov;
        }
    }
}

// ---------------------------------------------------------------------------
// Layer-3 aggregation v4: 4 slices of 256 ch (XCD pairs), records, float4
// partial stores into part[d][1024] (NO atomics -- R5 post-mortem; NO direct
// output fusion -- R10 post-mortem: losing the separate streamed comb3 for
// doubled gather footprint was net-negative). comb3 does mean+bias.
// ---------------------------------------------------------------------------
__global__ __launch_bounds__(256) void agg3s_kernel(
    const __hip_bfloat16* __restrict__ h, const uint2* __restrict__ rec,
    const int* __restrict__ off, float* __restrict__ part, int n)
{
    const int bid   = blockIdx.x;
    const int xcd   = bid & 7;
    const int slice = xcd >> 1;          // 0..3
    const int head  = slice >> 1;        // 0..1
    const int sb    = ((bid >> 3) << 1) | (xcd & 1);         // 0..511
    const int wvs   = sb * 4 + (threadIdx.x >> 6);           // 0..2047
    const int lane  = threadIdx.x & 63;
    const int half  = lane >> 5;
    const int c0    = slice * 256 + (lane & 31) * 8;
    const unsigned c0b = (unsigned)c0 * 2;
    const char* hb = (const char*)h;

    for (int d = wvs; d < n; d += 2048) {
        int beg = off[d], end = off[d + 1];
        float acc[8] = {0.f, 0.f, 0.f, 0.f, 0.f, 0.f, 0.f, 0.f};
        int i = beg + half;
        for (; i + 2 < end; i += 4) {
            uint2 r0 = rec[i * 2 + head];
            uint2 r1 = rec[(i + 2) * 2 + head];
            u16x8 v0 = *(const u16x8*)(hb + (size_t)(r0.x + c0b));
            u16x8 v1 = *(const u16x8*)(hb + (size_t)(r1.x + c0b));
            float a0 = __uint_as_float(r0.y);
            float a1 = __uint_as_float(r1.y);
            float f0[8], f1[8];
            bfx8_cvt(v0, f0);
            bfx8_cvt(v1, f1);
#pragma unroll
            for (int k = 0; k < 8; k++) acc[k] = fmaf(a0, f0[k], acc[k]);
#pragma unroll
            for (int k = 0; k < 8; k++) acc[k] = fmaf(a1, f1[k], acc[k]);
        }
        for (; i < end; i += 2) {
            uint2 r0 = rec[i * 2 + head];
            u16x8 v0 = *(const u16x8*)(hb + (size_t)(r0.x + c0b));
            float a0 = __uint_as_float(r0.y);
            float f0[8];
            bfx8_cvt(v0, f0);
#pragma unroll
            for (int k = 0; k < 8; k++) acc[k] = fmaf(a0, f0[k], acc[k]);
        }
#pragma unroll
        for (int k = 0; k < 8; k++) acc[k] += __shfl_xor(acc[k], 32);
        if (half == 0) {
            float* pp = part + (size_t)d * 1024 + c0;
            *(float4*)pp       = make_float4(acc[0], acc[1], acc[2], acc[3]);
            *(float4*)(pp + 4) = make_float4(acc[4], acc[5], acc[6], acc[7]);
        }
    }
}

// out[d][c] = 0.5*(part[d][c] + part[d][c+512]) + b3[c], c in [0,512)
__global__ void comb3_kernel(const float* __restrict__ part,
                             const float* __restrict__ b3,
                             float* __restrict__ out, int n) {
    int idx = blockIdx.x * 256 + threadIdx.x;
    if (idx >= n * 128) return;
    int d = idx >> 7, c = (idx & 127) * 4;
    float4 p0 = *(const float4*)(part + (size_t)d * 1024 + c);
    float4 p1 = *(const float4*)(part + (size_t)d * 1024 + 512 + c);
    float4 bb = *(const float4*)(b3 + c);
    float4 o;
    o.x = 0.5f * (p0.x + p1.x) + bb.x;
    o.y = 0.5f * (p0.y + p1.y) + bb.y;
    o.z = 0.5f * (p0.z + p1.z) + bb.z;
    o.w = 0.5f * (p0.w + p1.w) + bb.w;
    *(float4*)(out + (size_t)d * 512 + c) = o;
}

// ---------------------------------------------------------------------------
extern "C" void kernel_launch(void* const* d_in, const int* in_sizes, int n_in,
                              void* d_out, int out_size, void* d_ws, size_t ws_size,
                              hipStream_t stream) {
    const float* x      = (const float*)d_in[0];
    const int*   ei     = (const int*)  d_in[1];
    const float* proj_w = (const float*)d_in[2];
    const float* proj_b = (const float*)d_in[3];
    const float* w1  = (const float*)d_in[4];
    const float* as1 = (const float*)d_in[5];
    const float* ad1 = (const float*)d_in[6];
    const float* b1  = (const float*)d_in[7];
    const float* w2  = (const float*)d_in[8];
    const float* as2 = (const float*)d_in[9];
    const float* ad2 = (const float*)d_in[10];
    const float* b2  = (const float*)d_in[11];
    const float* w3  = (const float*)d_in[12];
    const float* as3 = (const float*)d_in[13];
    const float* ad3 = (const float*)d_in[14];
    const float* b3  = (const float*)d_in[15];

    const int n    = in_sizes[0] / 256;   // 10000
    const int E    = in_sizes[1] / 2;     // 160000
    const int Et   = E + n;               // 170000
    const int MB   = CDIV(n, 128);        // 79  (128-tile grid, layer 1)
    const int MB2  = CDIV(n, 256);        // 40  (256-tile grid)
    const int Mpad = MB2 * 256;           // 10240
    const int XT   = CDIV(MB, 8);         // 10

    char* p = (char*)d_ws;
    auto carve = [&](size_t bytes) {
        void* r = (void*)p;
        p += (bytes + 255) & ~(size_t)255;
        return r;
    };
    __hip_bfloat16* h_bf    = (__hip_bfloat16*)carve((size_t)Mpad * 2048 * sizeof(__hip_bfloat16));
    __hip_bfloat16* act_bf  = (__hip_bfloat16*)carve((size_t)Mpad * 2048 * sizeof(__hip_bfloat16));
    __hip_bfloat16* x_bf    = (__hip_bfloat16*)carve((size_t)Mpad * 256 * sizeof(__hip_bfloat16));
    __hip_bfloat16* pw_bf   = (__hip_bfloat16*)carve((size_t)256 * 512 * sizeof(__hip_bfloat16));
    __hip_bfloat16* w1t     = (__hip_bfloat16*)carve((size_t)2048 * 512 * sizeof(__hip_bfloat16));
    __hip_bfloat16* w2t     = (__hip_bfloat16*)carve((size_t)2048 * 2048 * sizeof(__hip_bfloat16));
    __hip_bfloat16* w3t     = (__hip_bfloat16*)carve((size_t)1024 * 2048 * sizeof(__hip_bfloat16));
    __hip_bfloat16* w_efft  = (__hip_bfloat16*)carve((size_t)2048 * 256 * sizeof(__hip_bfloat16));
    float* b_eff = (float*)carve((size_t)2048 * sizeof(float));
    float* b1s   = (float*)carve((size_t)2048 * sizeof(float));
    float* va    = (float*)carve((size_t)8 * 256 * sizeof(float));
    float* cvec  = (float*)carve((size_t)8 * sizeof(float));
    float* es  = (float*)carve((size_t)n * 4 * sizeof(float));
    float* ed  = (float*)carve((size_t)n * 4 * sizeof(float));
    uint2* rec = (uint2*)carve((size_t)Et * 4 * sizeof(uint2));   // {off,alpha} per (edge,head)
    int* deg = (int*)carve((size_t)2 * n * sizeof(int));   // deg + cur contiguous
    int* cur = deg + n;
    int* off = (int*)carve((size_t)(n + 1) * sizeof(int));
    int* csr = (int*)carve((size_t)Et * sizeof(int));
    __hip_bfloat16* z_bf = h_bf;   // layer-1 aggregated-x [Mpad,1024], overlays h_bf
    float* part = (float*)act_bf;  // layer-3 float partials [n,1024], overlays act_bf
    float4* al4 = (float4*)rec;    // layer-1 alpha float4 per edge, overlays rec
    (void)ws_size; (void)n_in;

    // --- CSR build ---
    hipMemsetAsync(deg, 0, 2 * n * sizeof(int), stream);
    hipMemsetAsync(b_eff, 0, 2048 * sizeof(float), stream);
    hist_kernel<<<CDIV(Et, 256), 256, 0, stream>>>(ei, deg, E, Et);
    scan_kernel<<<1, 1024, 0, stream>>>(deg, off, n);
    scatter_kernel<<<CDIV(Et, 256), 256, 0, stream>>>(ei, off, cur, csr, E, Et);

    // --- weight prep (fused) ---
    const int t0 = (512 / 32) * (2048 / 32);            // 1024
    const int t1 = t0 + (2048 / 32) * (2048 / 32);      // +4096
    const int t2 = t1 + (2048 / 32) * (1024 / 32);      // +2048
    prep_t_kernel<<<t2, 256, 0, stream>>>(w1, w1t, w2, w2t, w3, w3t, t0, t1, t2);
    const int na4 = 256 * 512 / 4, nb4 = n * 256 / 4;
    cvt2_kernel<<<CDIV(na4 + nb4, 256), 256, 0, stream>>>(proj_w, pw_bf, na4, x, x_bf, nb4);

    // --- fold proj into layer 1: W_eff^T[2048,256]; b_eff = proj_b @ w1 ---
    gemm_bf16_kernel<<<8 * 2 * 2, 256, 0, stream>>>(
        w1t, pw_bf, nullptr, w_efft, 2048, 256, 512, 512, 0, 0, 16, 2, 2, 2);
    beff_kernel<<<dim3(2048 / 256, 512 / 64), 256, 0, stream>>>(proj_b, w1, b_eff, 2048);

    // --- layer-1 attention vectors + constants; b1s = b_eff + b1 ---
    va_kernel<<<9, 256, 0, stream>>>(w_efft, b_eff, as1, ad1, b1, va, cvec, b1s);

    // --- layer 1, aggregated in input space (alpha precompute + vectorized) ---
    es1_kernel<<<n, 64, 0, stream>>>(x_bf, va, cvec, es, ed);
    alpha4_kernel<<<CDIV(n, 4), 256, 0, stream>>>(es, ed, csr, off, al4, n);
    agg1x_kernel<<<n, 256, 0, stream>>>(x_bf, al4, csr, off, z_bf);
    // act = ELU( z @ W_eff(per-head) + b_eff + b1 ): 128^2 kernel, 3 blk/CU
    gemm_bf16_kernel<<<8 * XT * 16, 256, 0, stream>>>(
        z_bf, w_efft, b1s, act_bf, n, 2048, 256, 1024, 256, 1, MB, 16, XT, 16);

    // --- layer 2 (H=4, concat): exact-256 big launch + exact-256 remainder ---
    gemm256_kernel<<<256, 512, 0, stream>>>(act_bf, w2t, h_bf, n, 2048, 2048, 40, 240);
    gemm128_kernel<<<256, 256, 0, stream>>>(act_bf, w2t, h_bf, n, 2048, 2048, 1, 0);
    esed_kernel<<<n, 4 * 64, 0, stream>>>(h_bf, as2, ad2, es, ed, 4);
    alpharec_kernel<4, 12><<<CDIV(n, 4), 256, 0, stream>>>(es, ed, csr, off, rec, n);
    agg2s_kernel<<<2048, 256, 0, stream>>>(h_bf, rec, off, b2, act_bf, n);

    // --- layer 3 (H=2): GEMM, records, partials + comb3 (mean+bias) ---
    gemm128_kernel<<<640, 256, 0, stream>>>(act_bf, w3t, h_bf, n, 1024, 2048, 0, 80);
    esed_kernel<<<n, 2 * 64, 0, stream>>>(h_bf, as3, ad3, es, ed, 2);
    alpharec_kernel<2, 11><<<CDIV(n, 4), 256, 0, stream>>>(es, ed, csr, off, rec, n);
    agg3s_kernel<<<2048, 256, 0, stream>>>(h_bf, rec, off, part, n);
    comb3_kernel<<<CDIV(n * 128, 256), 256, 0, stream>>>(part, b3, (float*)d_out, n);
}